// Round 1
// baseline (1311.282 us; speedup 1.0000x reference)
//
#include <hip/hip_runtime.h>
#include <hip/hip_bf16.h>
#include <math.h>

// Problem constants
#define N_CARDS 10000
#define HIDDEN  128
#define E       256
#define BATCH   16384
#define L       8
#define NH      4
#define HD      64

// ---------------------------------------------------------------------------
// K1: card embedding table: emb[c][0:128]=amp, emb[c][128:256]=phase
// ---------------------------------------------------------------------------
__global__ __launch_bounds__(128) void emb_kernel(
    const float* __restrict__ xr, const float* __restrict__ xi,
    float* __restrict__ emb) {
  int c = blockIdx.x;
  int d = threadIdx.x;
  float r  = xr[c * HIDDEN + d];
  float im = xi[c * HIDDEN + d];
  float amp = sqrtf(r * r + im * im + 1e-8f);
  float ph  = atan2f(im, r);
  emb[c * E + d]          = amp;
  emb[c * E + HIDDEN + d] = ph;
}

// ---------------------------------------------------------------------------
// K2: projection table GEMM.
// proj[c][n] = sum_k emb[c][k] * W[n][k] + bias[n]
//   n in [0,768)    -> in_w_my rows (q|k|v for MHA-my)
//   n in [768,1536) -> in_w_op rows (q|k|v for MHA-op)
// M=10000, N=1536, K=256. Tile 64x64, K-chunk 16, 4x4 per thread.
// ---------------------------------------------------------------------------
#define TM 64
#define TN 64
#define TK 16
__global__ __launch_bounds__(256) void proj_gemm(
    const float* __restrict__ emb,
    const float* __restrict__ wmy, const float* __restrict__ bmy,
    const float* __restrict__ wop, const float* __restrict__ bop,
    float* __restrict__ proj) {
  __shared__ float As[TK][TM + 1];  // [k][m]
  __shared__ float Bs[TK][TN + 1];  // [k][n]
  int m0 = blockIdx.x * TM;
  int n0 = blockIdx.y * TN;
  const float* W    = (n0 < 768) ? wmy : wop;
  const float* bias = (n0 < 768) ? bmy : bop;
  int nW = (n0 < 768) ? n0 : (n0 - 768);
  int tid = threadIdx.x;
  int tx = tid & 15, ty = tid >> 4;
  float acc[4][4] = {};

  for (int k0 = 0; k0 < E; k0 += TK) {
    int m  = tid >> 2;
    int kk = (tid & 3) * 4;
    int gm = m0 + m;
    float4 va = make_float4(0.f, 0.f, 0.f, 0.f);
    if (gm < N_CARDS) va = *(const float4*)(emb + (size_t)gm * E + k0 + kk);
    As[kk + 0][m] = va.x; As[kk + 1][m] = va.y;
    As[kk + 2][m] = va.z; As[kk + 3][m] = va.w;
    float4 vb = *(const float4*)(W + (size_t)(nW + m) * E + k0 + kk);
    Bs[kk + 0][m] = vb.x; Bs[kk + 1][m] = vb.y;
    Bs[kk + 2][m] = vb.z; Bs[kk + 3][m] = vb.w;
    __syncthreads();
#pragma unroll
    for (int k = 0; k < TK; ++k) {
      float a[4], b[4];
#pragma unroll
      for (int i = 0; i < 4; ++i) a[i] = As[k][ty * 4 + i];
#pragma unroll
      for (int i = 0; i < 4; ++i) b[i] = Bs[k][tx * 4 + i];
#pragma unroll
      for (int i = 0; i < 4; ++i)
#pragma unroll
        for (int j = 0; j < 4; ++j) acc[i][j] += a[i] * b[j];
    }
    __syncthreads();
  }
#pragma unroll
  for (int i = 0; i < 4; ++i) {
    int gm = m0 + ty * 4 + i;
    if (gm >= N_CARDS) break;
#pragma unroll
    for (int j = 0; j < 4; ++j) {
      int gn = n0 + tx * 4 + j;
      proj[(size_t)gm * 1536 + gn] = acc[i][j] + bias[nW + tx * 4 + j];
    }
  }
}

// ---------------------------------------------------------------------------
// K2b: fold out-projection into w1:
//   Wc_my[i][j] = sum_k w1[i][k]     * out_w_my[k][j]
//   Wc_op[i][j] = sum_k w1[i][256+k] * out_w_op[k][j]
//   bias_c[i]   = b1[i] + w1[i][:256]·out_b_my + w1[i][256:]·out_b_op
// ---------------------------------------------------------------------------
__global__ __launch_bounds__(256) void combine_w(
    const float* __restrict__ w1, const float* __restrict__ b1,
    const float* __restrict__ outw_my, const float* __restrict__ outb_my,
    const float* __restrict__ outw_op, const float* __restrict__ outb_op,
    float* __restrict__ wc_my, float* __restrict__ wc_op,
    float* __restrict__ bias_c) {
  int i = blockIdx.x;   // 0..255 (row of w1)
  int j = threadIdx.x;  // 0..255 (output col)
  float s_my = 0.f, s_op = 0.f;
  for (int k = 0; k < 256; ++k) {
    s_my += w1[i * 512 + k]       * outw_my[k * 256 + j];
    s_op += w1[i * 512 + 256 + k] * outw_op[k * 256 + j];
  }
  wc_my[i * 256 + j] = s_my;
  wc_op[i * 256 + j] = s_op;
  __shared__ float red[256];
  red[j] = w1[i * 512 + j] * outb_my[j] + w1[i * 512 + 256 + j] * outb_op[j];
  __syncthreads();
  for (int s = 128; s > 0; s >>= 1) {
    if (j < s) red[j] += red[j + s];
    __syncthreads();
  }
  if (j == 0) bias_c[i] = b1[i] + red[0];
}

// ---------------------------------------------------------------------------
// K3: per-batch attention. One 256-thread block per batch element.
// Gathers q/k/v rows for the 16 cards from the proj table, computes both
// cross-attentions, writes mean-over-queries PV outputs (pre-out-proj).
// LDS tables (row stride 264 to dodge bank conflicts), order:
//   0:qmy(my) 1:kmy(op) 2:vmy(op) 3:qop(op) 4:kop(my) 5:vop(my)
// ---------------------------------------------------------------------------
#define RSTR 264
__global__ __launch_bounds__(256) void attn_kernel(
    const float* __restrict__ proj,
    const int* __restrict__ my_decks, const int* __restrict__ op_decks,
    const int* __restrict__ adj,
    float* __restrict__ mean_my, float* __restrict__ mean_op) {
  __shared__ __align__(16) float tab[6 * 8 * RSTR];
  __shared__ int   cards[16];   // [0:8)=my, [8:16)=op
  __shared__ float biasm[8][8];
  __shared__ float wbar[2][NH][8];

  int b = blockIdx.x;
  int tid = threadIdx.x;

  if (tid < 8)        cards[tid] = my_decks[b * L + tid];
  else if (tid < 16)  cards[tid] = op_decks[b * L + tid - 8];
  __syncthreads();

  // gather 6 tables x 8 rows x 64 float4
#pragma unroll
  for (int it = 0; it < 12; ++it) {
    int idx = it * 256 + tid;       // 0..3071
    int t   = idx >> 9;             // table
    int rem = idx & 511;
    int r   = rem >> 6;             // row
    int c4  = rem & 63;             // float4 col
    int useMy = (0x31 >> t) & 1;    // tables 0,4,5 use my cards
    int card  = cards[useMy ? r : (8 + r)];
    float4 v = *(const float4*)(proj + (size_t)card * 1536 + t * 256 + c4 * 4);
    *(float4*)&tab[(t * 8 + r) * RSTR + c4 * 4] = v;
  }
  if (tid < 64) {
    int i = tid >> 3, j = tid & 7;
    int m = adj[(size_t)cards[i] * N_CARDS + cards[8 + j]];
    biasm[i][j] = (m > 0) ? 0.0f : -10000.0f;
  }
  __syncthreads();

  // scores + softmax + mean over queries; wave w handles head w for both MHAs
  int w    = tid >> 6;
  int lane = tid & 63;
  int i = lane >> 3, j = lane & 7;
  {
    // MHA-my: q = tab0[my i], k = tab1[op j], bias[i][j]
    const float4* q4 = (const float4*)&tab[(0 * 8 + i) * RSTR + w * HD];
    const float4* k4 = (const float4*)&tab[(1 * 8 + j) * RSTR + w * HD];
    float s = 0.f;
#pragma unroll
    for (int d = 0; d < 16; ++d) {
      float4 a = q4[d], bb = k4[d];
      s += a.x * bb.x + a.y * bb.y + a.z * bb.z + a.w * bb.w;
    }
    s = s * 0.125f + biasm[i][j];
    float mx = s;
    mx = fmaxf(mx, __shfl_xor(mx, 1));
    mx = fmaxf(mx, __shfl_xor(mx, 2));
    mx = fmaxf(mx, __shfl_xor(mx, 4));
    float e = expf(s - mx);
    float sum = e;
    sum += __shfl_xor(sum, 1); sum += __shfl_xor(sum, 2); sum += __shfl_xor(sum, 4);
    float a = e / sum;
    a += __shfl_xor(a, 8); a += __shfl_xor(a, 16); a += __shfl_xor(a, 32);
    if (lane < 8) wbar[0][w][lane] = a * 0.125f;
  }
  {
    // MHA-op: q = tab3[op i], k = tab4[my j], bias transposed -> biasm[j][i]
    const float4* q4 = (const float4*)&tab[(3 * 8 + i) * RSTR + w * HD];
    const float4* k4 = (const float4*)&tab[(4 * 8 + j) * RSTR + w * HD];
    float s = 0.f;
#pragma unroll
    for (int d = 0; d < 16; ++d) {
      float4 a = q4[d], bb = k4[d];
      s += a.x * bb.x + a.y * bb.y + a.z * bb.z + a.w * bb.w;
    }
    s = s * 0.125f + biasm[j][i];
    float mx = s;
    mx = fmaxf(mx, __shfl_xor(mx, 1));
    mx = fmaxf(mx, __shfl_xor(mx, 2));
    mx = fmaxf(mx, __shfl_xor(mx, 4));
    float e = expf(s - mx);
    float sum = e;
    sum += __shfl_xor(sum, 1); sum += __shfl_xor(sum, 2); sum += __shfl_xor(sum, 4);
    float a = e / sum;
    a += __shfl_xor(a, 8); a += __shfl_xor(a, 16); a += __shfl_xor(a, 32);
    if (lane < 8) wbar[1][w][lane] = a * 0.125f;
  }
  __syncthreads();

  // PV: out_mean[e] = sum_j wbar[h][j] * v[j][e], h = e/64
  {
    int e = tid;
    int h = e >> 6;
    float sm = 0.f, so = 0.f;
#pragma unroll
    for (int jj = 0; jj < 8; ++jj) {
      sm += wbar[0][h][jj] * tab[(2 * 8 + jj) * RSTR + e];
      so += wbar[1][h][jj] * tab[(5 * 8 + jj) * RSTR + e];
    }
    mean_my[(size_t)b * E + e] = sm;
    mean_op[(size_t)b * E + e] = so;
  }
}

// ---------------------------------------------------------------------------
// K4: fused MLP head. 8 batches per 256-thread block.
// h1 = mean_my@Wc_my^T + mean_op@Wc_op^T + bias_c ; LayerNorm; ReLU;
// h2 = relu(h1@w2^T + b2); logit = h2·w3 + b3
// ---------------------------------------------------------------------------
__global__ __launch_bounds__(256) void mlp_kernel(
    const float* __restrict__ mean_my, const float* __restrict__ mean_op,
    const float* __restrict__ wc_my, const float* __restrict__ wc_op,
    const float* __restrict__ bias_c,
    const float* __restrict__ ln_g, const float* __restrict__ ln_b,
    const float* __restrict__ w2, const float* __restrict__ b2,
    const float* __restrict__ w3, const float* __restrict__ b3,
    float* __restrict__ out) {
  __shared__ float mm[8][256];
  __shared__ float mo[8][256];
  __shared__ float h1s[8][257];
  __shared__ float h2s[8][64];
  __shared__ float stats[8][2];

  int b0 = blockIdx.x * 8;
  int tid = threadIdx.x;

#pragma unroll
  for (int it = 0; it < 2; ++it) {
    int idx = it * 256 + tid;  // float4 index, 0..511
    int q = idx >> 6;
    int c4 = idx & 63;
    *(float4*)&mm[q][c4 * 4] = *(const float4*)(mean_my + (size_t)(b0 + q) * E + c4 * 4);
    *(float4*)&mo[q][c4 * 4] = *(const float4*)(mean_op + (size_t)(b0 + q) * E + c4 * 4);
  }
  __syncthreads();

  int j = tid;
  float hq[8];
  float bc = bias_c[j];
#pragma unroll
  for (int q = 0; q < 8; ++q) hq[q] = bc;
  for (int k = 0; k < 256; ++k) {
    float wm = wc_my[(size_t)j * 256 + k];
    float wo = wc_op[(size_t)j * 256 + k];
#pragma unroll
    for (int q = 0; q < 8; ++q) hq[q] += wm * mm[q][k] + wo * mo[q][k];
  }
#pragma unroll
  for (int q = 0; q < 8; ++q) h1s[q][j] = hq[q];
  __syncthreads();

  int wv = tid >> 6, lane = tid & 63;
  for (int q2 = 0; q2 < 2; ++q2) {
    int q = wv * 2 + q2;
    float s = 0.f, ss = 0.f;
    for (int c = lane; c < 256; c += 64) {
      float v = h1s[q][c];
      s += v; ss += v * v;
    }
    for (int m = 1; m < 64; m <<= 1) {
      s  += __shfl_xor(s, m);
      ss += __shfl_xor(ss, m);
    }
    if (lane == 0) {
      float mu = s * (1.f / 256.f);
      float var = ss * (1.f / 256.f) - mu * mu;
      stats[q][0] = mu;
      stats[q][1] = rsqrtf(var + 1e-5f);
    }
  }
  __syncthreads();
  float g = ln_g[j], bb = ln_b[j];
#pragma unroll
  for (int q = 0; q < 8; ++q) {
    float v = (hq[q] - stats[q][0]) * stats[q][1] * g + bb;
    h1s[q][j] = fmaxf(v, 0.f);
  }
  __syncthreads();

  {
    int q = tid >> 5;
    int o = tid & 31;
    float s1 = b2[o], s2 = b2[o + 32];
    for (int k = 0; k < 256; ++k) {
      float hv = h1s[q][k];
      s1 += hv * w2[o * 256 + k];
      s2 += hv * w2[(o + 32) * 256 + k];
    }
    h2s[q][o]      = fmaxf(s1, 0.f);
    h2s[q][o + 32] = fmaxf(s2, 0.f);
  }
  __syncthreads();

  if (tid < 8) {
    float s = b3[0];
    for (int o = 0; o < 64; ++o) s += h2s[tid][o] * w3[o];
    out[b0 + tid] = s;
  }
}

// ---------------------------------------------------------------------------
extern "C" void kernel_launch(void* const* d_in, const int* in_sizes, int n_in,
                              void* d_out, int out_size, void* d_ws, size_t ws_size,
                              hipStream_t stream) {
  const float* x_real   = (const float*)d_in[0];
  const float* x_imag   = (const float*)d_in[1];
  const int*   my_decks = (const int*)d_in[2];
  const int*   op_decks = (const int*)d_in[3];
  const int*   adj      = (const int*)d_in[4];
  const float* in_w_my  = (const float*)d_in[5];
  const float* in_b_my  = (const float*)d_in[6];
  const float* out_w_my = (const float*)d_in[7];
  const float* out_b_my = (const float*)d_in[8];
  const float* in_w_op  = (const float*)d_in[9];
  const float* in_b_op  = (const float*)d_in[10];
  const float* out_w_op = (const float*)d_in[11];
  const float* out_b_op = (const float*)d_in[12];
  const float* w1       = (const float*)d_in[13];
  const float* b1       = (const float*)d_in[14];
  const float* ln_g     = (const float*)d_in[15];
  const float* ln_b     = (const float*)d_in[16];
  const float* w2       = (const float*)d_in[17];
  const float* b2       = (const float*)d_in[18];
  const float* w3       = (const float*)d_in[19];
  const float* b3       = (const float*)d_in[20];

  float* ws = (float*)d_ws;
  float* emb     = ws;                       // 10000*256       = 2,560,000
  float* proj    = emb + 2560000;            // 10000*1536      = 15,360,000
  float* meanmy  = proj + 15360000;          // 16384*256       = 4,194,304
  float* meanop  = meanmy + 4194304;         // 16384*256
  float* wc_my   = meanop + 4194304;         // 256*256
  float* wc_op   = wc_my + 65536;            // 256*256
  float* bias_c  = wc_op + 65536;            // 256
  float* out     = (float*)d_out;

  emb_kernel<<<N_CARDS, 128, 0, stream>>>(x_real, x_imag, emb);

  dim3 g2((N_CARDS + TM - 1) / TM, 1536 / TN);
  proj_gemm<<<g2, 256, 0, stream>>>(emb, in_w_my, in_b_my, in_w_op, in_b_op, proj);

  combine_w<<<256, 256, 0, stream>>>(w1, b1, out_w_my, out_b_my,
                                     out_w_op, out_b_op, wc_my, wc_op, bias_c);

  attn_kernel<<<BATCH, 256, 0, stream>>>(proj, my_decks, op_decks, adj,
                                         meanmy, meanop);

  mlp_kernel<<<BATCH / 8, 256, 0, stream>>>(meanmy, meanop, wc_my, wc_op, bias_c,
                                            ln_g, ln_b, w2, b2, w3, b3, out);
}

// Round 2
// 884.045 us; speedup vs baseline: 1.4833x; 1.4833x over previous
//
#include <hip/hip_runtime.h>
#include <hip/hip_bf16.h>
#include <math.h>

// Problem constants
#define N_CARDS 10000
#define HIDDEN  128
#define E       256
#define BATCH   16384
#define L       8
#define NH      4
#define HD      64

// ---------------------------------------------------------------------------
// K1: card embedding table: emb[c][0:128]=amp, emb[c][128:256]=phase
// ---------------------------------------------------------------------------
__global__ __launch_bounds__(128) void emb_kernel(
    const float* __restrict__ xr, const float* __restrict__ xi,
    float* __restrict__ emb) {
  int c = blockIdx.x;
  int d = threadIdx.x;
  float r  = xr[c * HIDDEN + d];
  float im = xi[c * HIDDEN + d];
  float amp = sqrtf(r * r + im * im + 1e-8f);
  float ph  = atan2f(im, r);
  emb[c * E + d]          = amp;
  emb[c * E + HIDDEN + d] = ph;
}

// ---------------------------------------------------------------------------
// K2: projection table GEMM.
// proj[c][n] = sum_k emb[c][k] * W[n][k] + bias[n]
// M=10000, N=1536, K=256. Tile 64x64, K-chunk 16, 4x4 per thread.
// ---------------------------------------------------------------------------
#define TM 64
#define TN 64
#define TK 16
__global__ __launch_bounds__(256) void proj_gemm(
    const float* __restrict__ emb,
    const float* __restrict__ wmy, const float* __restrict__ bmy,
    const float* __restrict__ wop, const float* __restrict__ bop,
    float* __restrict__ proj) {
  __shared__ float As[TK][TM + 1];  // [k][m]
  __shared__ float Bs[TK][TN + 1];  // [k][n]
  int m0 = blockIdx.x * TM;
  int n0 = blockIdx.y * TN;
  const float* W    = (n0 < 768) ? wmy : wop;
  const float* bias = (n0 < 768) ? bmy : bop;
  int nW = (n0 < 768) ? n0 : (n0 - 768);
  int tid = threadIdx.x;
  int tx = tid & 15, ty = tid >> 4;
  float acc[4][4] = {};

  for (int k0 = 0; k0 < E; k0 += TK) {
    int m  = tid >> 2;
    int kk = (tid & 3) * 4;
    int gm = m0 + m;
    float4 va = make_float4(0.f, 0.f, 0.f, 0.f);
    if (gm < N_CARDS) va = *(const float4*)(emb + (size_t)gm * E + k0 + kk);
    As[kk + 0][m] = va.x; As[kk + 1][m] = va.y;
    As[kk + 2][m] = va.z; As[kk + 3][m] = va.w;
    float4 vb = *(const float4*)(W + (size_t)(nW + m) * E + k0 + kk);
    Bs[kk + 0][m] = vb.x; Bs[kk + 1][m] = vb.y;
    Bs[kk + 2][m] = vb.z; Bs[kk + 3][m] = vb.w;
    __syncthreads();
#pragma unroll
    for (int k = 0; k < TK; ++k) {
      float a[4], b[4];
#pragma unroll
      for (int i = 0; i < 4; ++i) a[i] = As[k][ty * 4 + i];
#pragma unroll
      for (int i = 0; i < 4; ++i) b[i] = Bs[k][tx * 4 + i];
#pragma unroll
      for (int i = 0; i < 4; ++i)
#pragma unroll
        for (int j = 0; j < 4; ++j) acc[i][j] += a[i] * b[j];
    }
    __syncthreads();
  }
#pragma unroll
  for (int i = 0; i < 4; ++i) {
    int gm = m0 + ty * 4 + i;
    if (gm >= N_CARDS) break;
#pragma unroll
    for (int j = 0; j < 4; ++j) {
      int gn = n0 + tx * 4 + j;
      proj[(size_t)gm * 1536 + gn] = acc[i][j] + bias[nW + tx * 4 + j];
    }
  }
}

// ---------------------------------------------------------------------------
// K2b: fold out-projection into w1, storing TRANSPOSED [k][j] so that the
// downstream GEMM can stage B coalesced:
//   WcT_my[c][i] = sum_f w1[i][f]     * out_w_my[f][c]
//   WcT_op[c][i] = sum_f w1[i][256+f] * out_w_op[f][c]
//   bias_c[i]    = b1[i] + w1[i][:256]·out_b_my + w1[i][256:]·out_b_op
// ---------------------------------------------------------------------------
__global__ __launch_bounds__(256) void combine_w(
    const float* __restrict__ w1, const float* __restrict__ b1,
    const float* __restrict__ outw_my, const float* __restrict__ outb_my,
    const float* __restrict__ outw_op, const float* __restrict__ outb_op,
    float* __restrict__ wcT_my, float* __restrict__ wcT_op,
    float* __restrict__ bias_c) {
  int c = blockIdx.x;   // K index of Wc (col of out_w)
  int i = threadIdx.x;  // output index (row of w1)
  float s_my = 0.f, s_op = 0.f;
  for (int f = 0; f < 256; ++f) {
    float om = outw_my[f * 256 + c];  // uniform across lanes -> scalar load
    float oo = outw_op[f * 256 + c];
    s_my += w1[i * 512 + f]       * om;
    s_op += w1[i * 512 + 256 + f] * oo;
  }
  wcT_my[c * 256 + i] = s_my;  // coalesced
  wcT_op[c * 256 + i] = s_op;
  if (c == 0) {
    float s = b1[i];
    for (int f = 0; f < 256; ++f)
      s += w1[i * 512 + f] * outb_my[f] + w1[i * 512 + 256 + f] * outb_op[f];
    bias_c[i] = s;
  }
}

// ---------------------------------------------------------------------------
// K3: per-batch attention (unchanged this round).
// ---------------------------------------------------------------------------
#define RSTR 264
__global__ __launch_bounds__(256) void attn_kernel(
    const float* __restrict__ proj,
    const int* __restrict__ my_decks, const int* __restrict__ op_decks,
    const int* __restrict__ adj,
    float* __restrict__ mean_my, float* __restrict__ mean_op) {
  __shared__ __align__(16) float tab[6 * 8 * RSTR];
  __shared__ int   cards[16];
  __shared__ float biasm[8][8];
  __shared__ float wbar[2][NH][8];

  int b = blockIdx.x;
  int tid = threadIdx.x;

  if (tid < 8)        cards[tid] = my_decks[b * L + tid];
  else if (tid < 16)  cards[tid] = op_decks[b * L + tid - 8];
  __syncthreads();

#pragma unroll
  for (int it = 0; it < 12; ++it) {
    int idx = it * 256 + tid;
    int t   = idx >> 9;
    int rem = idx & 511;
    int r   = rem >> 6;
    int c4  = rem & 63;
    int useMy = (0x31 >> t) & 1;
    int card  = cards[useMy ? r : (8 + r)];
    float4 v = *(const float4*)(proj + (size_t)card * 1536 + t * 256 + c4 * 4);
    *(float4*)&tab[(t * 8 + r) * RSTR + c4 * 4] = v;
  }
  if (tid < 64) {
    int i = tid >> 3, j = tid & 7;
    int m = adj[(size_t)cards[i] * N_CARDS + cards[8 + j]];
    biasm[i][j] = (m > 0) ? 0.0f : -10000.0f;
  }
  __syncthreads();

  int w    = tid >> 6;
  int lane = tid & 63;
  int i = lane >> 3, j = lane & 7;
  {
    const float4* q4 = (const float4*)&tab[(0 * 8 + i) * RSTR + w * HD];
    const float4* k4 = (const float4*)&tab[(1 * 8 + j) * RSTR + w * HD];
    float s = 0.f;
#pragma unroll
    for (int d = 0; d < 16; ++d) {
      float4 a = q4[d], bb = k4[d];
      s += a.x * bb.x + a.y * bb.y + a.z * bb.z + a.w * bb.w;
    }
    s = s * 0.125f + biasm[i][j];
    float mx = s;
    mx = fmaxf(mx, __shfl_xor(mx, 1));
    mx = fmaxf(mx, __shfl_xor(mx, 2));
    mx = fmaxf(mx, __shfl_xor(mx, 4));
    float e = expf(s - mx);
    float sum = e;
    sum += __shfl_xor(sum, 1); sum += __shfl_xor(sum, 2); sum += __shfl_xor(sum, 4);
    float a = e / sum;
    a += __shfl_xor(a, 8); a += __shfl_xor(a, 16); a += __shfl_xor(a, 32);
    if (lane < 8) wbar[0][w][lane] = a * 0.125f;
  }
  {
    const float4* q4 = (const float4*)&tab[(3 * 8 + i) * RSTR + w * HD];
    const float4* k4 = (const float4*)&tab[(4 * 8 + j) * RSTR + w * HD];
    float s = 0.f;
#pragma unroll
    for (int d = 0; d < 16; ++d) {
      float4 a = q4[d], bb = k4[d];
      s += a.x * bb.x + a.y * bb.y + a.z * bb.z + a.w * bb.w;
    }
    s = s * 0.125f + biasm[j][i];
    float mx = s;
    mx = fmaxf(mx, __shfl_xor(mx, 1));
    mx = fmaxf(mx, __shfl_xor(mx, 2));
    mx = fmaxf(mx, __shfl_xor(mx, 4));
    float e = expf(s - mx);
    float sum = e;
    sum += __shfl_xor(sum, 1); sum += __shfl_xor(sum, 2); sum += __shfl_xor(sum, 4);
    float a = e / sum;
    a += __shfl_xor(a, 8); a += __shfl_xor(a, 16); a += __shfl_xor(a, 32);
    if (lane < 8) wbar[1][w][lane] = a * 0.125f;
  }
  __syncthreads();

  {
    int e = tid;
    int h = e >> 6;
    float sm = 0.f, so = 0.f;
#pragma unroll
    for (int jj = 0; jj < 8; ++jj) {
      sm += wbar[0][h][jj] * tab[(2 * 8 + jj) * RSTR + e];
      so += wbar[1][h][jj] * tab[(5 * 8 + jj) * RSTR + e];
    }
    mean_my[(size_t)b * E + e] = sm;
    mean_op[(size_t)b * E + e] = so;
  }
}

// ---------------------------------------------------------------------------
// K4a: h1 GEMM + bias + LayerNorm + ReLU, fused per 32-row tile.
// h1[b][j] = sum_k A[b][k] * Wc[j][k],  A=[mean_my | mean_op] (K=512).
// Tile: M=32, N=256 (full row -> LN in-block). 256 thr, 4x8 micro-tile.
// Output written in place over mean_my (each block reads its rows fully
// before writing; blocks own disjoint rows).
// ---------------------------------------------------------------------------
#define GM 32
__global__ __launch_bounds__(256) void gemm_ln(
    const float* __restrict__ meanmy, const float* __restrict__ meanop,
    const float* __restrict__ wcT_my, const float* __restrict__ wcT_op,
    const float* __restrict__ bias_c,
    const float* __restrict__ ln_g, const float* __restrict__ ln_b,
    float* __restrict__ hbuf) {
  __shared__ __align__(16) float As[16][GM + 4];   // [k][m]
  __shared__ __align__(16) float Bs[16][260];      // [k][j]
  int m0 = blockIdx.x * GM;
  int tid = threadIdx.x;
  int tx = tid & 31, ty = tid >> 5;
  float acc[4][8] = {};

  for (int k0 = 0; k0 < 512; k0 += 16) {
    const float* Asrc = (k0 < 256) ? meanmy : meanop;
    const float* Bsrc = (k0 < 256) ? wcT_my : wcT_op;
    int kb = k0 & 255;
    if (tid < 128) {
      int m = tid >> 2, kk = (tid & 3) * 4;
      float4 v = *(const float4*)(Asrc + (size_t)(m0 + m) * 256 + kb + kk);
      As[kk + 0][m] = v.x; As[kk + 1][m] = v.y;
      As[kk + 2][m] = v.z; As[kk + 3][m] = v.w;
    }
#pragma unroll
    for (int r = 0; r < 4; ++r) {
      int kr = r * 4 + (tid >> 6);
      int c4 = tid & 63;
      *(float4*)&Bs[kr][c4 * 4] =
          *(const float4*)(Bsrc + (size_t)(kb + kr) * 256 + c4 * 4);
    }
    __syncthreads();
#pragma unroll
    for (int k = 0; k < 16; ++k) {
      float4 av = *(const float4*)&As[k][ty * 4];
      float a[4] = {av.x, av.y, av.z, av.w};
      float4 b0 = *(const float4*)&Bs[k][tx * 4];
      float4 b1v = *(const float4*)&Bs[k][128 + tx * 4];
      float b[8] = {b0.x, b0.y, b0.z, b0.w, b1v.x, b1v.y, b1v.z, b1v.w};
#pragma unroll
      for (int i = 0; i < 4; ++i)
#pragma unroll
        for (int j = 0; j < 8; ++j) acc[i][j] += a[i] * b[j];
    }
    __syncthreads();
  }

  // bias + LN + relu
  float bc[8], g[8], bb[8];
#pragma unroll
  for (int jj = 0; jj < 8; ++jj) {
    int cgl = (jj < 4) ? (tx * 4 + jj) : (128 + tx * 4 + (jj - 4));
    bc[jj] = bias_c[cgl]; g[jj] = ln_g[cgl]; bb[jj] = ln_b[cgl];
  }
#pragma unroll
  for (int i = 0; i < 4; ++i) {
    float s = 0.f, ss = 0.f;
#pragma unroll
    for (int jj = 0; jj < 8; ++jj) {
      float v = acc[i][jj] + bc[jj];
      acc[i][jj] = v;
      s += v; ss += v * v;
    }
    s  += __shfl_xor(s, 1);  ss += __shfl_xor(ss, 1);
    s  += __shfl_xor(s, 2);  ss += __shfl_xor(ss, 2);
    s  += __shfl_xor(s, 4);  ss += __shfl_xor(ss, 4);
    s  += __shfl_xor(s, 8);  ss += __shfl_xor(ss, 8);
    s  += __shfl_xor(s, 16); ss += __shfl_xor(ss, 16);
    float mu = s * (1.f / 256.f);
    float rsig = rsqrtf(ss * (1.f / 256.f) - mu * mu + 1e-5f);
#pragma unroll
    for (int jj = 0; jj < 8; ++jj) {
      float v = (acc[i][jj] - mu) * rsig * g[jj] + bb[jj];
      acc[i][jj] = fmaxf(v, 0.f);
    }
    int row = m0 + ty * 4 + i;
    float4 o0 = make_float4(acc[i][0], acc[i][1], acc[i][2], acc[i][3]);
    float4 o1 = make_float4(acc[i][4], acc[i][5], acc[i][6], acc[i][7]);
    *(float4*)(hbuf + (size_t)row * 256 + tx * 4) = o0;
    *(float4*)(hbuf + (size_t)row * 256 + 128 + tx * 4) = o1;
  }
}

// ---------------------------------------------------------------------------
// K4b: h2 = relu(h@w2^T + b2); logit = h2·w3 + b3. 8 batches per block.
// ---------------------------------------------------------------------------
__global__ __launch_bounds__(256) void head_kernel(
    const float* __restrict__ hbuf,
    const float* __restrict__ w2, const float* __restrict__ b2,
    const float* __restrict__ w3, const float* __restrict__ b3,
    float* __restrict__ out) {
  __shared__ __align__(16) float w2s[64][260];
  __shared__ __align__(16) float hs[8][260];
  __shared__ float h2s[8][66];
  __shared__ float w3s[64];
  int b0 = blockIdx.x * 8;
  int tid = threadIdx.x;

#pragma unroll
  for (int it = 0; it < 16; ++it) {
    int idx = it * 256 + tid;
    int r = idx >> 6, c4 = idx & 63;
    *(float4*)&w2s[r][c4 * 4] = *(const float4*)(w2 + r * 256 + c4 * 4);
  }
#pragma unroll
  for (int it = 0; it < 2; ++it) {
    int idx = it * 256 + tid;
    int q = idx >> 6, c4 = idx & 63;
    *(float4*)&hs[q][c4 * 4] =
        *(const float4*)(hbuf + (size_t)(b0 + q) * 256 + c4 * 4);
  }
  if (tid < 64) w3s[tid] = w3[tid];
  __syncthreads();

  int q = tid >> 5, o = tid & 31;
  float s1 = b2[o], s2 = b2[o + 32];
  for (int k4 = 0; k4 < 64; ++k4) {
    float4 hv = *(const float4*)&hs[q][k4 * 4];
    float4 wa = *(const float4*)&w2s[o][k4 * 4];
    float4 wb = *(const float4*)&w2s[o + 32][k4 * 4];
    s1 += hv.x * wa.x + hv.y * wa.y + hv.z * wa.z + hv.w * wa.w;
    s2 += hv.x * wb.x + hv.y * wb.y + hv.z * wb.z + hv.w * wb.w;
  }
  h2s[q][o]      = fmaxf(s1, 0.f);
  h2s[q][o + 32] = fmaxf(s2, 0.f);
  __syncthreads();

  if (tid < 8) {
    float s = b3[0];
    for (int o2 = 0; o2 < 64; ++o2) s += h2s[tid][o2] * w3s[o2];
    out[b0 + tid] = s;
  }
}

// ---------------------------------------------------------------------------
extern "C" void kernel_launch(void* const* d_in, const int* in_sizes, int n_in,
                              void* d_out, int out_size, void* d_ws, size_t ws_size,
                              hipStream_t stream) {
  const float* x_real   = (const float*)d_in[0];
  const float* x_imag   = (const float*)d_in[1];
  const int*   my_decks = (const int*)d_in[2];
  const int*   op_decks = (const int*)d_in[3];
  const int*   adj      = (const int*)d_in[4];
  const float* in_w_my  = (const float*)d_in[5];
  const float* in_b_my  = (const float*)d_in[6];
  const float* out_w_my = (const float*)d_in[7];
  const float* out_b_my = (const float*)d_in[8];
  const float* in_w_op  = (const float*)d_in[9];
  const float* in_b_op  = (const float*)d_in[10];
  const float* out_w_op = (const float*)d_in[11];
  const float* out_b_op = (const float*)d_in[12];
  const float* w1       = (const float*)d_in[13];
  const float* b1       = (const float*)d_in[14];
  const float* ln_g     = (const float*)d_in[15];
  const float* ln_b     = (const float*)d_in[16];
  const float* w2       = (const float*)d_in[17];
  const float* b2       = (const float*)d_in[18];
  const float* w3       = (const float*)d_in[19];
  const float* b3       = (const float*)d_in[20];

  float* ws = (float*)d_ws;
  float* emb     = ws;                       // 10000*256
  float* proj    = emb + 2560000;            // 10000*1536
  float* meanmy  = proj + 15360000;          // 16384*256 (reused as hbuf)
  float* meanop  = meanmy + 4194304;         // 16384*256
  float* wcT_my  = meanop + 4194304;         // 256*256
  float* wcT_op  = wcT_my + 65536;           // 256*256
  float* bias_c  = wcT_op + 65536;           // 256
  float* out     = (float*)d_out;

  emb_kernel<<<N_CARDS, 128, 0, stream>>>(x_real, x_imag, emb);

  dim3 g2((N_CARDS + TM - 1) / TM, 1536 / TN);
  proj_gemm<<<g2, 256, 0, stream>>>(emb, in_w_my, in_b_my, in_w_op, in_b_op, proj);

  combine_w<<<256, 256, 0, stream>>>(w1, b1, out_w_my, out_b_my,
                                     out_w_op, out_b_op, wcT_my, wcT_op, bias_c);

  attn_kernel<<<BATCH, 256, 0, stream>>>(proj, my_decks, op_decks, adj,
                                         meanmy, meanop);

  gemm_ln<<<BATCH / GM, 256, 0, stream>>>(meanmy, meanop, wcT_my, wcT_op,
                                          bias_c, ln_g, ln_b, meanmy);

  head_kernel<<<BATCH / 8, 256, 0, stream>>>(meanmy, w2, b2, w3, b3, out);
}

// Round 3
// 762.529 us; speedup vs baseline: 1.7196x; 1.1594x over previous
//
#include <hip/hip_runtime.h>
#include <hip/hip_bf16.h>
#include <math.h>

// Problem constants
#define N_CARDS 10000
#define HIDDEN  128
#define E       256
#define BATCH   16384
#define L       8
#define NH      4
#define HD      64

typedef __attribute__((ext_vector_type(8))) short short8;
typedef __attribute__((ext_vector_type(4))) float f32x4;
typedef unsigned short ust;

__device__ __forceinline__ f32x4 mfma16(short8 a, short8 b, f32x4 c) {
  return __builtin_amdgcn_mfma_f32_16x16x32_bf16(a, b, c, 0, 0, 0);
}
// split f32 -> hi bf16 (truncate) + lo bf16 (remainder); 3-term MFMA gives
// ~3e-5 relative error (al*bl term dropped).
__device__ __forceinline__ void split2(float x, ust& h, ust& l) {
  unsigned u = __float_as_uint(x);
  h = (ust)(u >> 16);
  float r = x - __uint_as_float(u & 0xFFFF0000u);
  l = (ust)(__float_as_uint(r) >> 16);
}

// ---------------------------------------------------------------------------
// K1: card embedding table
// ---------------------------------------------------------------------------
__global__ __launch_bounds__(128) void emb_kernel(
    const float* __restrict__ xr, const float* __restrict__ xi,
    float* __restrict__ emb) {
  int c = blockIdx.x;
  int d = threadIdx.x;
  float r  = xr[c * HIDDEN + d];
  float im = xi[c * HIDDEN + d];
  float amp = sqrtf(r * r + im * im + 1e-8f);
  float ph  = atan2f(im, r);
  emb[c * E + d]          = amp;
  emb[c * E + HIDDEN + d] = ph;
}

// ---------------------------------------------------------------------------
// K2: projection table GEMM via split-bf16 MFMA (3-term, f32-grade accuracy).
// proj[c][n] = sum_k emb[c][k]*W[n][k] + bias[n]. M=10000,N=1536,K=256.
// Block tile 64x64, BK=64, 4 waves in 2x2, each wave 2x2 of 16x16x32.
// ---------------------------------------------------------------------------
#define PSTR 72   // 64 + 8 shorts pad: row stride 144B (16B-aligned, 2-way LDS)
__global__ __launch_bounds__(256) void proj_mfma(
    const float* __restrict__ emb,
    const float* __restrict__ wmy, const float* __restrict__ bmy,
    const float* __restrict__ wop, const float* __restrict__ bop,
    float* __restrict__ proj) {
  __shared__ __align__(16) ust sA[2][64 * PSTR];
  __shared__ __align__(16) ust sB[2][64 * PSTR];
  int m0 = blockIdx.x * 64;
  int n0 = blockIdx.y * 64;
  const float* W    = (n0 < 768) ? wmy : wop;
  const float* bias = (n0 < 768) ? bmy : bop;
  int nW = (n0 < 768) ? n0 : n0 - 768;
  int tid = threadIdx.x;
  int w = tid >> 6, lane = tid & 63;
  int wm = w >> 1, wn = w & 1;
  int lrow = lane & 15, lq = lane >> 4;

  f32x4 acc[2][2] = {};
  int arow = tid >> 2;
  int acol = (tid & 3) * 16;
  int gm = m0 + arow;
  const float* aptr = emb + (size_t)gm * 256;
  const float* bptr = W + (size_t)(nW + arow) * 256;

  for (int kb = 0; kb < 256; kb += 64) {
#pragma unroll
    for (int i = 0; i < 4; ++i) {
      int kk = acol + i * 4;
      float4 va = (gm < N_CARDS) ? *(const float4*)(aptr + kb + kk)
                                 : make_float4(0.f, 0.f, 0.f, 0.f);
      ushort4 hv, lv;
      split2(va.x, hv.x, lv.x); split2(va.y, hv.y, lv.y);
      split2(va.z, hv.z, lv.z); split2(va.w, hv.w, lv.w);
      *(ushort4*)&sA[0][arow * PSTR + kk] = hv;
      *(ushort4*)&sA[1][arow * PSTR + kk] = lv;
      float4 vb = *(const float4*)(bptr + kb + kk);
      split2(vb.x, hv.x, lv.x); split2(vb.y, hv.y, lv.y);
      split2(vb.z, hv.z, lv.z); split2(vb.w, hv.w, lv.w);
      *(ushort4*)&sB[0][arow * PSTR + kk] = hv;
      *(ushort4*)&sB[1][arow * PSTR + kk] = lv;
    }
    __syncthreads();
#pragma unroll
    for (int ks = 0; ks < 64; ks += 32) {
      short8 ah[2], al[2], bh[2], bl[2];
#pragma unroll
      for (int t = 0; t < 2; ++t) {
        int ko = ks + lq * 8;
        int ar = wm * 32 + t * 16 + lrow;
        ah[t] = *(const short8*)&sA[0][ar * PSTR + ko];
        al[t] = *(const short8*)&sA[1][ar * PSTR + ko];
        int br = wn * 32 + t * 16 + lrow;
        bh[t] = *(const short8*)&sB[0][br * PSTR + ko];
        bl[t] = *(const short8*)&sB[1][br * PSTR + ko];
      }
#pragma unroll
      for (int i = 0; i < 2; ++i)
#pragma unroll
        for (int j = 0; j < 2; ++j) {
          acc[i][j] = mfma16(ah[i], bh[j], acc[i][j]);
          acc[i][j] = mfma16(ah[i], bl[j], acc[i][j]);
          acc[i][j] = mfma16(al[i], bh[j], acc[i][j]);
        }
    }
    __syncthreads();
  }
#pragma unroll
  for (int i = 0; i < 2; ++i) {
    int mrow0 = m0 + wm * 32 + i * 16 + lq * 4;
#pragma unroll
    for (int j = 0; j < 2; ++j) {
      int ncol = wn * 32 + j * 16 + lrow;
      float bv = bias[nW + ncol];
#pragma unroll
      for (int r = 0; r < 4; ++r) {
        int m = mrow0 + r;
        if (m < N_CARDS)
          proj[(size_t)m * 1536 + n0 + ncol] = acc[i][j][r] + bv;
      }
    }
  }
}

// ---------------------------------------------------------------------------
// K2b: Wcomb[i][k] = w1[i][:256]@outw_my (k<256) / w1[i][256:]@outw_op,
// emitted as bf16 hi/lo planes [i][k] (MFMA B-operand friendly).
// Tile 64(i) x 64(k), K=256 over f. grid (4, 8).
// ---------------------------------------------------------------------------
__global__ __launch_bounds__(256) void combine_w(
    const float* __restrict__ w1,
    const float* __restrict__ owmy, const float* __restrict__ owop,
    ust* __restrict__ wch, ust* __restrict__ wcl) {
  __shared__ float As[16][65];  // [f][i]
  __shared__ float Bs[16][65];  // [f][k]
  int i0 = blockIdx.x * 64;
  int kt = blockIdx.y;  // 0..7
  const float* OW = (kt < 4) ? owmy : owop;
  int k0 = (kt & 3) * 64;
  int foff = (kt < 4) ? 0 : 256;
  int tid = threadIdx.x;
  int tx = tid & 15, ty = tid >> 4;
  float acc[4][4] = {};
  for (int f0 = 0; f0 < 256; f0 += 16) {
    {
      int i = tid >> 2, ff = (tid & 3) * 4;
      float4 v = *(const float4*)&w1[(size_t)(i0 + i) * 512 + foff + f0 + ff];
      As[ff + 0][i] = v.x; As[ff + 1][i] = v.y;
      As[ff + 2][i] = v.z; As[ff + 3][i] = v.w;
      int f = tid >> 4, kk = (tid & 15) * 4;
      float4 b = *(const float4*)&OW[(size_t)(f0 + f) * 256 + k0 + kk];
      Bs[f][kk + 0] = b.x; Bs[f][kk + 1] = b.y;
      Bs[f][kk + 2] = b.z; Bs[f][kk + 3] = b.w;
    }
    __syncthreads();
#pragma unroll
    for (int f = 0; f < 16; ++f) {
      float a[4], b[4];
#pragma unroll
      for (int i = 0; i < 4; ++i) a[i] = As[f][ty * 4 + i];
#pragma unroll
      for (int j = 0; j < 4; ++j) b[j] = Bs[f][tx * 4 + j];
#pragma unroll
      for (int i = 0; i < 4; ++i)
#pragma unroll
        for (int j = 0; j < 4; ++j) acc[i][j] += a[i] * b[j];
    }
    __syncthreads();
  }
#pragma unroll
  for (int i = 0; i < 4; ++i)
#pragma unroll
    for (int j = 0; j < 4; ++j) {
      int gi = i0 + ty * 4 + i;
      int gk = kt * 64 + tx * 4 + j;
      ust h, l;
      split2(acc[i][j], h, l);
      wch[(size_t)gi * 512 + gk] = h;
      wcl[(size_t)gi * 512 + gk] = l;
    }
}

// bias_c[i] = b1[i] + w1[i][:256]·out_b_my + w1[i][256:]·out_b_op
__global__ __launch_bounds__(256) void bias_kernel(
    const float* __restrict__ w1, const float* __restrict__ b1,
    const float* __restrict__ obm, const float* __restrict__ obo,
    float* __restrict__ bias_c) {
  int i = threadIdx.x;
  float s = b1[i];
  for (int f = 0; f < 256; f += 4) {
    float4 wa = *(const float4*)&w1[(size_t)i * 512 + f];
    float4 ba = *(const float4*)&obm[f];
    float4 wb = *(const float4*)&w1[(size_t)i * 512 + 256 + f];
    float4 bo = *(const float4*)&obo[f];
    s += wa.x * ba.x + wa.y * ba.y + wa.z * ba.z + wa.w * ba.w;
    s += wb.x * bo.x + wb.y * bo.y + wb.z * bo.z + wb.w * bo.w;
  }
  bias_c[i] = s;
}

// ---------------------------------------------------------------------------
// K3: per-batch attention (unchanged).
// ---------------------------------------------------------------------------
#define RSTR 264
__global__ __launch_bounds__(256) void attn_kernel(
    const float* __restrict__ proj,
    const int* __restrict__ my_decks, const int* __restrict__ op_decks,
    const int* __restrict__ adj,
    float* __restrict__ mean_my, float* __restrict__ mean_op) {
  __shared__ __align__(16) float tab[6 * 8 * RSTR];
  __shared__ int   cards[16];
  __shared__ float biasm[8][8];
  __shared__ float wbar[2][NH][8];

  int b = blockIdx.x;
  int tid = threadIdx.x;

  if (tid < 8)        cards[tid] = my_decks[b * L + tid];
  else if (tid < 16)  cards[tid] = op_decks[b * L + tid - 8];
  __syncthreads();

#pragma unroll
  for (int it = 0; it < 12; ++it) {
    int idx = it * 256 + tid;
    int t   = idx >> 9;
    int rem = idx & 511;
    int r   = rem >> 6;
    int c4  = rem & 63;
    int useMy = (0x31 >> t) & 1;
    int card  = cards[useMy ? r : (8 + r)];
    float4 v = *(const float4*)(proj + (size_t)card * 1536 + t * 256 + c4 * 4);
    *(float4*)&tab[(t * 8 + r) * RSTR + c4 * 4] = v;
  }
  if (tid < 64) {
    int i = tid >> 3, j = tid & 7;
    int m = adj[(size_t)cards[i] * N_CARDS + cards[8 + j]];
    biasm[i][j] = (m > 0) ? 0.0f : -10000.0f;
  }
  __syncthreads();

  int w    = tid >> 6;
  int lane = tid & 63;
  int i = lane >> 3, j = lane & 7;
  {
    const float4* q4 = (const float4*)&tab[(0 * 8 + i) * RSTR + w * HD];
    const float4* k4 = (const float4*)&tab[(1 * 8 + j) * RSTR + w * HD];
    float s = 0.f;
#pragma unroll
    for (int d = 0; d < 16; ++d) {
      float4 a = q4[d], bb = k4[d];
      s += a.x * bb.x + a.y * bb.y + a.z * bb.z + a.w * bb.w;
    }
    s = s * 0.125f + biasm[i][j];
    float mx = s;
    mx = fmaxf(mx, __shfl_xor(mx, 1));
    mx = fmaxf(mx, __shfl_xor(mx, 2));
    mx = fmaxf(mx, __shfl_xor(mx, 4));
    float e = expf(s - mx);
    float sum = e;
    sum += __shfl_xor(sum, 1); sum += __shfl_xor(sum, 2); sum += __shfl_xor(sum, 4);
    float a = e / sum;
    a += __shfl_xor(a, 8); a += __shfl_xor(a, 16); a += __shfl_xor(a, 32);
    if (lane < 8) wbar[0][w][lane] = a * 0.125f;
  }
  {
    const float4* q4 = (const float4*)&tab[(3 * 8 + i) * RSTR + w * HD];
    const float4* k4 = (const float4*)&tab[(4 * 8 + j) * RSTR + w * HD];
    float s = 0.f;
#pragma unroll
    for (int d = 0; d < 16; ++d) {
      float4 a = q4[d], bb = k4[d];
      s += a.x * bb.x + a.y * bb.y + a.z * bb.z + a.w * bb.w;
    }
    s = s * 0.125f + biasm[j][i];
    float mx = s;
    mx = fmaxf(mx, __shfl_xor(mx, 1));
    mx = fmaxf(mx, __shfl_xor(mx, 2));
    mx = fmaxf(mx, __shfl_xor(mx, 4));
    float e = expf(s - mx);
    float sum = e;
    sum += __shfl_xor(sum, 1); sum += __shfl_xor(sum, 2); sum += __shfl_xor(sum, 4);
    float a = e / sum;
    a += __shfl_xor(a, 8); a += __shfl_xor(a, 16); a += __shfl_xor(a, 32);
    if (lane < 8) wbar[1][w][lane] = a * 0.125f;
  }
  __syncthreads();

  {
    int e = tid;
    int h = e >> 6;
    float sm = 0.f, so = 0.f;
#pragma unroll
    for (int jj = 0; jj < 8; ++jj) {
      sm += wbar[0][h][jj] * tab[(2 * 8 + jj) * RSTR + e];
      so += wbar[1][h][jj] * tab[(5 * 8 + jj) * RSTR + e];
    }
    mean_my[(size_t)b * E + e] = sm;
    mean_op[(size_t)b * E + e] = so;
  }
}

// ---------------------------------------------------------------------------
// K4a: h1 GEMM (split-bf16 MFMA) + bias + LN + ReLU fused.
// M=16384,N=256,K=512. Block tile 32x256, BK=32. 4 waves, wave = 32x64.
// ---------------------------------------------------------------------------
#define GSTR 40  // 32 + 8 shorts pad
__global__ __launch_bounds__(256) void gemm_ln_mfma(
    const float* __restrict__ meanmy, const float* __restrict__ meanop,
    const ust* __restrict__ wch, const ust* __restrict__ wcl,
    const float* __restrict__ bias_c,
    const float* __restrict__ ln_g, const float* __restrict__ ln_b,
    float* __restrict__ hbuf) {
  __shared__ __align__(16) char smem[46080];
  ust* sAh = (ust*)smem;          // 32*40 shorts
  ust* sAl = sAh + 32 * GSTR;
  ust* sBh = sAl + 32 * GSTR;     // 256*40 shorts
  ust* sBl = sBh + 256 * GSTR;
  float* h1s = (float*)smem;      // reused after GEMM: 32 x 260

  int m0 = blockIdx.x * 32;
  int tid = threadIdx.x;
  int w = tid >> 6, lane = tid & 63;
  int lrow = lane & 15, lq = lane >> 4;
  int cb = w * 64;

  f32x4 acc[2][4] = {};
  int ar = tid >> 3;        // 0..31
  int ak = (tid & 7) * 4;   // 0..28

  for (int it = 0; it < 16; ++it) {
    int kb = it * 32;
    const float* Asrc = (kb < 256) ? meanmy : meanop;
    int kbl = kb & 255;
    {
      float4 va = *(const float4*)(Asrc + (size_t)(m0 + ar) * 256 + kbl + ak);
      ushort4 hv, lv;
      split2(va.x, hv.x, lv.x); split2(va.y, hv.y, lv.y);
      split2(va.z, hv.z, lv.z); split2(va.w, hv.w, lv.w);
      *(ushort4*)&sAh[ar * GSTR + ak] = hv;
      *(ushort4*)&sAl[ar * GSTR + ak] = lv;
    }
#pragma unroll
    for (int s = 0; s < 8; ++s) {
      int n = s * 32 + ar;
      *(uint2*)&sBh[n * GSTR + ak] = *(const uint2*)&wch[(size_t)n * 512 + kb + ak];
      *(uint2*)&sBl[n * GSTR + ak] = *(const uint2*)&wcl[(size_t)n * 512 + kb + ak];
    }
    __syncthreads();
    short8 ah[2], al[2];
#pragma unroll
    for (int t = 0; t < 2; ++t) {
      int r = t * 16 + lrow;
      ah[t] = *(const short8*)&sAh[r * GSTR + lq * 8];
      al[t] = *(const short8*)&sAl[r * GSTR + lq * 8];
    }
#pragma unroll
    for (int j = 0; j < 4; ++j) {
      int n = cb + j * 16 + lrow;
      short8 bh = *(const short8*)&sBh[n * GSTR + lq * 8];
      short8 bl = *(const short8*)&sBl[n * GSTR + lq * 8];
#pragma unroll
      for (int t = 0; t < 2; ++t) {
        acc[t][j] = mfma16(ah[t], bh, acc[t][j]);
        acc[t][j] = mfma16(ah[t], bl, acc[t][j]);
        acc[t][j] = mfma16(al[t], bh, acc[t][j]);
      }
    }
    __syncthreads();
  }

  // write h1 (+bias_c) into reused LDS (all MFMA reads done: loop-final barrier)
#pragma unroll
  for (int t = 0; t < 2; ++t)
#pragma unroll
    for (int j = 0; j < 4; ++j) {
      int col = cb + j * 16 + lrow;
      float bv = bias_c[col];
#pragma unroll
      for (int r = 0; r < 4; ++r) {
        int row = t * 16 + lq * 4 + r;
        h1s[row * 260 + col] = acc[t][j][r] + bv;
      }
    }
  __syncthreads();

  float g[4], bb[4];
#pragma unroll
  for (int s = 0; s < 4; ++s) {
    g[s]  = ln_g[lane + s * 64];
    bb[s] = ln_b[lane + s * 64];
  }
  for (int q = 0; q < 8; ++q) {
    int row = w * 8 + q;
    float v[4]; float sum = 0.f, ss = 0.f;
#pragma unroll
    for (int s = 0; s < 4; ++s) {
      v[s] = h1s[row * 260 + lane + s * 64];
      sum += v[s]; ss += v[s] * v[s];
    }
    for (int m = 1; m < 64; m <<= 1) {
      sum += __shfl_xor(sum, m);
      ss  += __shfl_xor(ss, m);
    }
    float mu = sum * (1.f / 256.f);
    float rs = rsqrtf(ss * (1.f / 256.f) - mu * mu + 1e-5f);
#pragma unroll
    for (int s = 0; s < 4; ++s) {
      float o = fmaxf((v[s] - mu) * rs * g[s] + bb[s], 0.f);
      hbuf[(size_t)(m0 + row) * 256 + lane + s * 64] = o;
    }
  }
}

// ---------------------------------------------------------------------------
// K4b: head (unchanged).
// ---------------------------------------------------------------------------
__global__ __launch_bounds__(256) void head_kernel(
    const float* __restrict__ hbuf,
    const float* __restrict__ w2, const float* __restrict__ b2,
    const float* __restrict__ w3, const float* __restrict__ b3,
    float* __restrict__ out) {
  __shared__ __align__(16) float w2s[64][260];
  __shared__ __align__(16) float hs[8][260];
  __shared__ float h2s[8][66];
  __shared__ float w3s[64];
  int b0 = blockIdx.x * 8;
  int tid = threadIdx.x;

#pragma unroll
  for (int it = 0; it < 16; ++it) {
    int idx = it * 256 + tid;
    int r = idx >> 6, c4 = idx & 63;
    *(float4*)&w2s[r][c4 * 4] = *(const float4*)(w2 + r * 256 + c4 * 4);
  }
#pragma unroll
  for (int it = 0; it < 2; ++it) {
    int idx = it * 256 + tid;
    int q = idx >> 6, c4 = idx & 63;
    *(float4*)&hs[q][c4 * 4] =
        *(const float4*)(hbuf + (size_t)(b0 + q) * 256 + c4 * 4);
  }
  if (tid < 64) w3s[tid] = w3[tid];
  __syncthreads();

  int q = tid >> 5, o = tid & 31;
  float s1 = b2[o], s2 = b2[o + 32];
  for (int k4 = 0; k4 < 64; ++k4) {
    float4 hv = *(const float4*)&hs[q][k4 * 4];
    float4 wa = *(const float4*)&w2s[o][k4 * 4];
    float4 wb = *(const float4*)&w2s[o + 32][k4 * 4];
    s1 += hv.x * wa.x + hv.y * wa.y + hv.z * wa.z + hv.w * wa.w;
    s2 += hv.x * wb.x + hv.y * wb.y + hv.z * wb.z + hv.w * wb.w;
  }
  h2s[q][o]      = fmaxf(s1, 0.f);
  h2s[q][o + 32] = fmaxf(s2, 0.f);
  __syncthreads();

  if (tid < 8) {
    float s = b3[0];
    for (int o2 = 0; o2 < 64; ++o2) s += h2s[tid][o2] * w3s[o2];
    out[b0 + tid] = s;
  }
}

// ---------------------------------------------------------------------------
extern "C" void kernel_launch(void* const* d_in, const int* in_sizes, int n_in,
                              void* d_out, int out_size, void* d_ws, size_t ws_size,
                              hipStream_t stream) {
  const float* x_real   = (const float*)d_in[0];
  const float* x_imag   = (const float*)d_in[1];
  const int*   my_decks = (const int*)d_in[2];
  const int*   op_decks = (const int*)d_in[3];
  const int*   adj      = (const int*)d_in[4];
  const float* in_w_my  = (const float*)d_in[5];
  const float* in_b_my  = (const float*)d_in[6];
  const float* out_w_my = (const float*)d_in[7];
  const float* out_b_my = (const float*)d_in[8];
  const float* in_w_op  = (const float*)d_in[9];
  const float* in_b_op  = (const float*)d_in[10];
  const float* out_w_op = (const float*)d_in[11];
  const float* out_b_op = (const float*)d_in[12];
  const float* w1       = (const float*)d_in[13];
  const float* b1       = (const float*)d_in[14];
  const float* ln_g     = (const float*)d_in[15];
  const float* ln_b     = (const float*)d_in[16];
  const float* w2       = (const float*)d_in[17];
  const float* b2       = (const float*)d_in[18];
  const float* w3       = (const float*)d_in[19];
  const float* b3       = (const float*)d_in[20];

  float* ws = (float*)d_ws;
  float* emb     = ws;                       // 10000*256
  float* proj    = emb + 2560000;            // 10000*1536
  float* meanmy  = proj + 15360000;          // 16384*256 (reused as hbuf)
  float* meanop  = meanmy + 4194304;         // 16384*256
  float* bias_c  = meanop + 4194304;         // 256
  ust*   wch     = (ust*)(bias_c + 256);     // 256*512 shorts
  ust*   wcl     = wch + 131072;             // 256*512 shorts
  float* out     = (float*)d_out;

  emb_kernel<<<N_CARDS, 128, 0, stream>>>(x_real, x_imag, emb);

  dim3 g2((N_CARDS + 63) / 64, 1536 / 64);
  proj_mfma<<<g2, 256, 0, stream>>>(emb, in_w_my, in_b_my, in_w_op, in_b_op, proj);

  combine_w<<<dim3(4, 8), 256, 0, stream>>>(w1, out_w_my, out_w_op, wch, wcl);
  bias_kernel<<<1, 256, 0, stream>>>(w1, b1, out_b_my, out_b_op, bias_c);

  attn_kernel<<<BATCH, 256, 0, stream>>>(proj, my_decks, op_decks, adj,
                                         meanmy, meanop);

  gemm_ln_mfma<<<BATCH / 32, 256, 0, stream>>>(meanmy, meanop, wch, wcl, bias_c,
                                               ln_g, ln_b, meanmy);

  head_kernel<<<BATCH / 8, 256, 0, stream>>>(meanmy, w2, b2, w3, b3, out);
}

// Round 4
// 731.445 us; speedup vs baseline: 1.7927x; 1.0425x over previous
//
#include <hip/hip_runtime.h>
#include <hip/hip_bf16.h>
#include <math.h>

// Problem constants
#define N_CARDS 10000
#define HIDDEN  128
#define E       256
#define BATCH   16384
#define L       8
#define NH      4
#define HD      64

typedef __attribute__((ext_vector_type(8))) short short8;
typedef __attribute__((ext_vector_type(4))) float f32x4;
typedef unsigned short ust;

__device__ __forceinline__ f32x4 mfma16(short8 a, short8 b, f32x4 c) {
  return __builtin_amdgcn_mfma_f32_16x16x32_bf16(a, b, c, 0, 0, 0);
}
// split f32 -> hi bf16 (truncate) + lo bf16 (remainder); 3-term MFMA gives
// ~3e-5 relative error (al*bl term dropped).
__device__ __forceinline__ void split2(float x, ust& h, ust& l) {
  unsigned u = __float_as_uint(x);
  h = (ust)(u >> 16);
  float r = x - __uint_as_float(u & 0xFFFF0000u);
  l = (ust)(__float_as_uint(r) >> 16);
}

// ---------------------------------------------------------------------------
// K1: card embedding, pre-split into bf16 hi/lo planes [c][0:128]=amp,
// [c][128:256]=phase.
// ---------------------------------------------------------------------------
__global__ __launch_bounds__(128) void emb_kernel(
    const float* __restrict__ xr, const float* __restrict__ xi,
    ust* __restrict__ embh, ust* __restrict__ embl) {
  int c = blockIdx.x;
  int d = threadIdx.x;
  float r  = xr[c * HIDDEN + d];
  float im = xi[c * HIDDEN + d];
  float amp = sqrtf(r * r + im * im + 1e-8f);
  float ph  = atan2f(im, r);
  ust h, l;
  split2(amp, h, l);
  embh[c * E + d] = h; embl[c * E + d] = l;
  split2(ph, h, l);
  embh[c * E + HIDDEN + d] = h; embl[c * E + HIDDEN + d] = l;
}

// ---------------------------------------------------------------------------
// K1b: split stacked projection weights [in_w_my; in_w_op] (1536 x 256)
// into bf16 hi/lo planes.
// ---------------------------------------------------------------------------
__global__ __launch_bounds__(256) void wsplit(
    const float* __restrict__ wmy, const float* __restrict__ wop,
    ust* __restrict__ wbh, ust* __restrict__ wbl) {
  int idx = blockIdx.x * 256 + threadIdx.x;   // float4 index over 1536*256/4
  int row = idx >> 6, c4 = idx & 63;
  const float* src = (row < 768) ? (wmy + (size_t)row * 256)
                                 : (wop + (size_t)(row - 768) * 256);
  float4 v = *(const float4*)(src + c4 * 4);
  ushort4 h, l;
  split2(v.x, h.x, l.x); split2(v.y, h.y, l.y);
  split2(v.z, h.z, l.z); split2(v.w, h.w, l.w);
  *(ushort4*)&wbh[(size_t)row * 256 + c4 * 4] = h;
  *(ushort4*)&wbl[(size_t)row * 256 + c4 * 4] = l;
}

// ---------------------------------------------------------------------------
// K2: projection table GEMM via split-bf16 MFMA. M=10000(pad 10112), N=1536,
// K=256. Block tile 128x128, BK=64, 4 waves 2x2, wave = 64x64 (4x4 MFMA).
// Inputs pre-split -> staging is pure 16B copies.
// ---------------------------------------------------------------------------
#define PSTR 72
__global__ __launch_bounds__(256) void proj_mfma(
    const ust* __restrict__ embh, const ust* __restrict__ embl,
    const ust* __restrict__ wbh, const ust* __restrict__ wbl,
    const float* __restrict__ bmy, const float* __restrict__ bop,
    float* __restrict__ proj) {
  __shared__ __align__(16) ust sAh[128 * PSTR];
  __shared__ __align__(16) ust sAl[128 * PSTR];
  __shared__ __align__(16) ust sBh[128 * PSTR];
  __shared__ __align__(16) ust sBl[128 * PSTR];
  int m0 = blockIdx.x * 128;
  int n0 = blockIdx.y * 128;
  int tid = threadIdx.x;
  int w = tid >> 6, lane = tid & 63;
  int wm = w >> 1, wn = w & 1;
  int lrow = lane & 15, lq = lane >> 4;

  f32x4 acc[4][4] = {};

  for (int kb = 0; kb < 256; kb += 64) {
#pragma unroll
    for (int rep = 0; rep < 4; ++rep) {
      int idx = rep * 256 + tid;       // 0..1023
      int row = idx >> 3, ch = (idx & 7) * 8;
      int gm = m0 + row;
      short8 ah = {}, al = {};
      if (gm < N_CARDS) {
        ah = *(const short8*)&embh[(size_t)gm * 256 + kb + ch];
        al = *(const short8*)&embl[(size_t)gm * 256 + kb + ch];
      }
      *(short8*)&sAh[row * PSTR + ch] = ah;
      *(short8*)&sAl[row * PSTR + ch] = al;
      int gn = n0 + row;
      *(short8*)&sBh[row * PSTR + ch] = *(const short8*)&wbh[(size_t)gn * 256 + kb + ch];
      *(short8*)&sBl[row * PSTR + ch] = *(const short8*)&wbl[(size_t)gn * 256 + kb + ch];
    }
    __syncthreads();
#pragma unroll
    for (int ks = 0; ks < 2; ++ks) {
      int ko = ks * 32 + lq * 8;
      short8 ah[4], al[4], bh[4], bl[4];
#pragma unroll
      for (int i = 0; i < 4; ++i) {
        int ar = wm * 64 + i * 16 + lrow;
        ah[i] = *(const short8*)&sAh[ar * PSTR + ko];
        al[i] = *(const short8*)&sAl[ar * PSTR + ko];
        int br = wn * 64 + i * 16 + lrow;
        bh[i] = *(const short8*)&sBh[br * PSTR + ko];
        bl[i] = *(const short8*)&sBl[br * PSTR + ko];
      }
#pragma unroll
      for (int i = 0; i < 4; ++i)
#pragma unroll
        for (int j = 0; j < 4; ++j) {
          acc[i][j] = mfma16(ah[i], bh[j], acc[i][j]);
          acc[i][j] = mfma16(ah[i], bl[j], acc[i][j]);
          acc[i][j] = mfma16(al[i], bh[j], acc[i][j]);
        }
    }
    __syncthreads();
  }

  const float* bias = (n0 < 768) ? bmy : bop;
  int nbase = (n0 < 768) ? n0 : n0 - 768;
#pragma unroll
  for (int j = 0; j < 4; ++j) {
    int ncol = wn * 64 + j * 16 + lrow;
    float bv = bias[nbase + ncol];
#pragma unroll
    for (int i = 0; i < 4; ++i) {
      int mrow0 = m0 + wm * 64 + i * 16 + lq * 4;
#pragma unroll
      for (int r = 0; r < 4; ++r) {
        int m = mrow0 + r;
        if (m < N_CARDS)
          proj[(size_t)m * 1536 + n0 + ncol] = acc[i][j][r] + bv;
      }
    }
  }
}

// ---------------------------------------------------------------------------
// K2b: Wcomb[i][k] (bf16 hi/lo planes, layout [i][k] k in [0,512)).
// block = (i, half); lanes sweep k' coalesced over ow rows; w1 row is
// wave-uniform -> scalar loads.
// ---------------------------------------------------------------------------
__global__ __launch_bounds__(256) void combine_w(
    const float* __restrict__ w1,
    const float* __restrict__ owmy, const float* __restrict__ owop,
    ust* __restrict__ wch, ust* __restrict__ wcl) {
  int i = blockIdx.x;
  int half = blockIdx.y;
  int kp = threadIdx.x;
  const float* ow = half ? owop : owmy;
  const float* w1r = w1 + (size_t)i * 512 + half * 256;
  float s = 0.f;
#pragma unroll 4
  for (int f = 0; f < 256; ++f) {
    s += w1r[f] * ow[(size_t)f * 256 + kp];
  }
  ust h, l;
  split2(s, h, l);
  wch[(size_t)i * 512 + half * 256 + kp] = h;
  wcl[(size_t)i * 512 + half * 256 + kp] = l;
}

// bias_c[i] = b1[i] + w1[i][:256]·out_b_my + w1[i][256:]·out_b_op
__global__ __launch_bounds__(256) void bias_kernel(
    const float* __restrict__ w1, const float* __restrict__ b1,
    const float* __restrict__ obm, const float* __restrict__ obo,
    float* __restrict__ bias_c) {
  int i = threadIdx.x;
  float s = b1[i];
  for (int f = 0; f < 256; f += 4) {
    float4 wa = *(const float4*)&w1[(size_t)i * 512 + f];
    float4 ba = *(const float4*)&obm[f];
    float4 wb = *(const float4*)&w1[(size_t)i * 512 + 256 + f];
    float4 bo = *(const float4*)&obo[f];
    s += wa.x * ba.x + wa.y * ba.y + wa.z * ba.z + wa.w * ba.w;
    s += wb.x * bo.x + wb.y * bo.y + wb.z * bo.z + wb.w * bo.w;
  }
  bias_c[i] = s;
}

// ---------------------------------------------------------------------------
// K3: per-batch attention, two-phase LDS (Q/K then V reusing slots).
// LDS ~34 KB -> 4 blocks/CU. Slots phase1: 0=qmy(my) 1=kmy(op) 2=qop(op)
// 3=kop(my); phase2: 0=vmy(op) 1=vop(my).
// ---------------------------------------------------------------------------
#define ASTR 260
__global__ __launch_bounds__(256) void attn_kernel(
    const float* __restrict__ proj,
    const int* __restrict__ my_decks, const int* __restrict__ op_decks,
    const int* __restrict__ adj,
    float* __restrict__ mean_my, float* __restrict__ mean_op) {
  __shared__ __align__(16) float tab[4 * 8 * ASTR];
  __shared__ int   cards[16];
  __shared__ float biasm[8][8];
  __shared__ float wbar[2][NH][8];

  int b = blockIdx.x;
  int tid = threadIdx.x;

  if (tid < 8)        cards[tid] = my_decks[b * L + tid];
  else if (tid < 16)  cards[tid] = op_decks[b * L + tid - 8];
  __syncthreads();

  // phase-1 gather: qmy, kmy, qop, kop (proj col-blocks 0,1,3,4)
#pragma unroll
  for (int it = 0; it < 8; ++it) {
    int idx = it * 256 + tid;        // 0..2047
    int t   = idx >> 9;
    int r   = (idx >> 6) & 7;
    int c4  = idx & 63;
    int tp  = (t == 0) ? 0 : (t == 1) ? 1 : (t == 2) ? 3 : 4;
    int useMy = (t == 0) | (t == 3);
    int card  = cards[useMy ? r : (8 + r)];
    float4 v = *(const float4*)(proj + (size_t)card * 1536 + tp * 256 + c4 * 4);
    *(float4*)&tab[(t * 8 + r) * ASTR + c4 * 4] = v;
  }
  if (tid < 64) {
    int i = tid >> 3, j = tid & 7;
    int m = adj[(size_t)cards[i] * N_CARDS + cards[8 + j]];
    biasm[i][j] = (m > 0) ? 0.0f : -10000.0f;
  }
  __syncthreads();

  int w    = tid >> 6;
  int lane = tid & 63;
  int i = lane >> 3, j = lane & 7;
  {
    const float4* q4 = (const float4*)&tab[(0 * 8 + i) * ASTR + w * HD];
    const float4* k4 = (const float4*)&tab[(1 * 8 + j) * ASTR + w * HD];
    float s = 0.f;
#pragma unroll
    for (int d = 0; d < 16; ++d) {
      float4 a = q4[d], bb = k4[d];
      s += a.x * bb.x + a.y * bb.y + a.z * bb.z + a.w * bb.w;
    }
    s = s * 0.125f + biasm[i][j];
    float mx = s;
    mx = fmaxf(mx, __shfl_xor(mx, 1));
    mx = fmaxf(mx, __shfl_xor(mx, 2));
    mx = fmaxf(mx, __shfl_xor(mx, 4));
    float e = expf(s - mx);
    float sum = e;
    sum += __shfl_xor(sum, 1); sum += __shfl_xor(sum, 2); sum += __shfl_xor(sum, 4);
    float a = e / sum;
    a += __shfl_xor(a, 8); a += __shfl_xor(a, 16); a += __shfl_xor(a, 32);
    if (lane < 8) wbar[0][w][lane] = a * 0.125f;
  }
  {
    const float4* q4 = (const float4*)&tab[(2 * 8 + i) * ASTR + w * HD];
    const float4* k4 = (const float4*)&tab[(3 * 8 + j) * ASTR + w * HD];
    float s = 0.f;
#pragma unroll
    for (int d = 0; d < 16; ++d) {
      float4 a = q4[d], bb = k4[d];
      s += a.x * bb.x + a.y * bb.y + a.z * bb.z + a.w * bb.w;
    }
    s = s * 0.125f + biasm[j][i];
    float mx = s;
    mx = fmaxf(mx, __shfl_xor(mx, 1));
    mx = fmaxf(mx, __shfl_xor(mx, 2));
    mx = fmaxf(mx, __shfl_xor(mx, 4));
    float e = expf(s - mx);
    float sum = e;
    sum += __shfl_xor(sum, 1); sum += __shfl_xor(sum, 2); sum += __shfl_xor(sum, 4);
    float a = e / sum;
    a += __shfl_xor(a, 8); a += __shfl_xor(a, 16); a += __shfl_xor(a, 32);
    if (lane < 8) wbar[1][w][lane] = a * 0.125f;
  }
  __syncthreads();  // QK LDS reads complete; safe to overwrite slots 0,1

  // phase-2 gather: vmy (op cards, proj block 2) -> slot 0;
  //                 vop (my cards, proj block 5) -> slot 1
#pragma unroll
  for (int it = 0; it < 4; ++it) {
    int idx = it * 256 + tid;        // 0..1023
    int t   = idx >> 9;
    int r   = (idx >> 6) & 7;
    int c4  = idx & 63;
    int card = cards[t == 0 ? (8 + r) : r];
    int tp   = t == 0 ? 2 : 5;
    float4 v = *(const float4*)(proj + (size_t)card * 1536 + tp * 256 + c4 * 4);
    *(float4*)&tab[(t * 8 + r) * ASTR + c4 * 4] = v;
  }
  __syncthreads();

  {
    int e = tid;
    int h = e >> 6;
    float sm = 0.f, so = 0.f;
#pragma unroll
    for (int jj = 0; jj < 8; ++jj) {
      sm += wbar[0][h][jj] * tab[(0 * 8 + jj) * ASTR + e];
      so += wbar[1][h][jj] * tab[(1 * 8 + jj) * ASTR + e];
    }
    mean_my[(size_t)b * E + e] = sm;
    mean_op[(size_t)b * E + e] = so;
  }
}

// ---------------------------------------------------------------------------
// K4a: h1 GEMM (split-bf16 MFMA) + bias + LN + ReLU fused. (unchanged)
// ---------------------------------------------------------------------------
#define GSTR 40
__global__ __launch_bounds__(256) void gemm_ln_mfma(
    const float* __restrict__ meanmy, const float* __restrict__ meanop,
    const ust* __restrict__ wch, const ust* __restrict__ wcl,
    const float* __restrict__ bias_c,
    const float* __restrict__ ln_g, const float* __restrict__ ln_b,
    float* __restrict__ hbuf) {
  __shared__ __align__(16) char smem[46080];
  ust* sAh = (ust*)smem;
  ust* sAl = sAh + 32 * GSTR;
  ust* sBh = sAl + 32 * GSTR;
  ust* sBl = sBh + 256 * GSTR;
  float* h1s = (float*)smem;

  int m0 = blockIdx.x * 32;
  int tid = threadIdx.x;
  int w = tid >> 6, lane = tid & 63;
  int lrow = lane & 15, lq = lane >> 4;
  int cb = w * 64;

  f32x4 acc[2][4] = {};
  int ar = tid >> 3;
  int ak = (tid & 7) * 4;

  for (int it = 0; it < 16; ++it) {
    int kb = it * 32;
    const float* Asrc = (kb < 256) ? meanmy : meanop;
    int kbl = kb & 255;
    {
      float4 va = *(const float4*)(Asrc + (size_t)(m0 + ar) * 256 + kbl + ak);
      ushort4 hv, lv;
      split2(va.x, hv.x, lv.x); split2(va.y, hv.y, lv.y);
      split2(va.z, hv.z, lv.z); split2(va.w, hv.w, lv.w);
      *(ushort4*)&sAh[ar * GSTR + ak] = hv;
      *(ushort4*)&sAl[ar * GSTR + ak] = lv;
    }
#pragma unroll
    for (int s = 0; s < 8; ++s) {
      int n = s * 32 + ar;
      *(uint2*)&sBh[n * GSTR + ak] = *(const uint2*)&wch[(size_t)n * 512 + kb + ak];
      *(uint2*)&sBl[n * GSTR + ak] = *(const uint2*)&wcl[(size_t)n * 512 + kb + ak];
    }
    __syncthreads();
    short8 ah[2], al[2];
#pragma unroll
    for (int t = 0; t < 2; ++t) {
      int r = t * 16 + lrow;
      ah[t] = *(const short8*)&sAh[r * GSTR + lq * 8];
      al[t] = *(const short8*)&sAl[r * GSTR + lq * 8];
    }
#pragma unroll
    for (int j = 0; j < 4; ++j) {
      int n = cb + j * 16 + lrow;
      short8 bh = *(const short8*)&sBh[n * GSTR + lq * 8];
      short8 bl = *(const short8*)&sBl[n * GSTR + lq * 8];
#pragma unroll
      for (int t = 0; t < 2; ++t) {
        acc[t][j] = mfma16(ah[t], bh, acc[t][j]);
        acc[t][j] = mfma16(ah[t], bl, acc[t][j]);
        acc[t][j] = mfma16(al[t], bh, acc[t][j]);
      }
    }
    __syncthreads();
  }

#pragma unroll
  for (int t = 0; t < 2; ++t)
#pragma unroll
    for (int j = 0; j < 4; ++j) {
      int col = cb + j * 16 + lrow;
      float bv = bias_c[col];
#pragma unroll
      for (int r = 0; r < 4; ++r) {
        int row = t * 16 + lq * 4 + r;
        h1s[row * 260 + col] = acc[t][j][r] + bv;
      }
    }
  __syncthreads();

  float g[4], bb[4];
#pragma unroll
  for (int s = 0; s < 4; ++s) {
    g[s]  = ln_g[lane + s * 64];
    bb[s] = ln_b[lane + s * 64];
  }
  for (int q = 0; q < 8; ++q) {
    int row = w * 8 + q;
    float v[4]; float sum = 0.f, ss = 0.f;
#pragma unroll
    for (int s = 0; s < 4; ++s) {
      v[s] = h1s[row * 260 + lane + s * 64];
      sum += v[s]; ss += v[s] * v[s];
    }
    for (int m = 1; m < 64; m <<= 1) {
      sum += __shfl_xor(sum, m);
      ss  += __shfl_xor(ss, m);
    }
    float mu = sum * (1.f / 256.f);
    float rs = rsqrtf(ss * (1.f / 256.f) - mu * mu + 1e-5f);
#pragma unroll
    for (int s = 0; s < 4; ++s) {
      float o = fmaxf((v[s] - mu) * rs * g[s] + bb[s], 0.f);
      hbuf[(size_t)(m0 + row) * 256 + lane + s * 64] = o;
    }
  }
}

// ---------------------------------------------------------------------------
// K4b: head (unchanged).
// ---------------------------------------------------------------------------
__global__ __launch_bounds__(256) void head_kernel(
    const float* __restrict__ hbuf,
    const float* __restrict__ w2, const float* __restrict__ b2,
    const float* __restrict__ w3, const float* __restrict__ b3,
    float* __restrict__ out) {
  __shared__ __align__(16) float w2s[64][260];
  __shared__ __align__(16) float hs[8][260];
  __shared__ float h2s[8][66];
  __shared__ float w3s[64];
  int b0 = blockIdx.x * 8;
  int tid = threadIdx.x;

#pragma unroll
  for (int it = 0; it < 16; ++it) {
    int idx = it * 256 + tid;
    int r = idx >> 6, c4 = idx & 63;
    *(float4*)&w2s[r][c4 * 4] = *(const float4*)(w2 + r * 256 + c4 * 4);
  }
#pragma unroll
  for (int it = 0; it < 2; ++it) {
    int idx = it * 256 + tid;
    int q = idx >> 6, c4 = idx & 63;
    *(float4*)&hs[q][c4 * 4] =
        *(const float4*)(hbuf + (size_t)(b0 + q) * 256 + c4 * 4);
  }
  if (tid < 64) w3s[tid] = w3[tid];
  __syncthreads();

  int q = tid >> 5, o = tid & 31;
  float s1 = b2[o], s2 = b2[o + 32];
  for (int k4 = 0; k4 < 64; ++k4) {
    float4 hv = *(const float4*)&hs[q][k4 * 4];
    float4 wa = *(const float4*)&w2s[o][k4 * 4];
    float4 wb = *(const float4*)&w2s[o + 32][k4 * 4];
    s1 += hv.x * wa.x + hv.y * wa.y + hv.z * wa.z + hv.w * wa.w;
    s2 += hv.x * wb.x + hv.y * wb.y + hv.z * wb.z + hv.w * wb.w;
  }
  h2s[q][o]      = fmaxf(s1, 0.f);
  h2s[q][o + 32] = fmaxf(s2, 0.f);
  __syncthreads();

  if (tid < 8) {
    float s = b3[0];
    for (int o2 = 0; o2 < 64; ++o2) s += h2s[tid][o2] * w3s[o2];
    out[b0 + tid] = s;
  }
}

// ---------------------------------------------------------------------------
extern "C" void kernel_launch(void* const* d_in, const int* in_sizes, int n_in,
                              void* d_out, int out_size, void* d_ws, size_t ws_size,
                              hipStream_t stream) {
  const float* x_real   = (const float*)d_in[0];
  const float* x_imag   = (const float*)d_in[1];
  const int*   my_decks = (const int*)d_in[2];
  const int*   op_decks = (const int*)d_in[3];
  const int*   adj      = (const int*)d_in[4];
  const float* in_w_my  = (const float*)d_in[5];
  const float* in_b_my  = (const float*)d_in[6];
  const float* out_w_my = (const float*)d_in[7];
  const float* out_b_my = (const float*)d_in[8];
  const float* in_w_op  = (const float*)d_in[9];
  const float* in_b_op  = (const float*)d_in[10];
  const float* out_w_op = (const float*)d_in[11];
  const float* out_b_op = (const float*)d_in[12];
  const float* w1       = (const float*)d_in[13];
  const float* b1       = (const float*)d_in[14];
  const float* ln_g     = (const float*)d_in[15];
  const float* ln_b     = (const float*)d_in[16];
  const float* w2       = (const float*)d_in[17];
  const float* b2       = (const float*)d_in[18];
  const float* w3       = (const float*)d_in[19];
  const float* b3       = (const float*)d_in[20];

  float* ws = (float*)d_ws;
  float* proj    = ws;                       // 10000*1536 f32
  float* meanmy  = proj + 15360000;          // 16384*256 (reused as hbuf)
  float* meanop  = meanmy + 4194304;
  float* bias_c  = meanop + 4194304;         // 256
  ust*   wch     = (ust*)(bias_c + 256);     // 256*512 ust
  ust*   wcl     = wch + 131072;
  ust*   embh    = wcl + 131072;             // 10000*256 ust
  ust*   embl    = embh + 2560000;
  ust*   wbh     = embl + 2560000;           // 1536*256 ust
  ust*   wbl     = wbh + 393216;
  float* out     = (float*)d_out;

  emb_kernel<<<N_CARDS, 128, 0, stream>>>(x_real, x_imag, embh, embl);

  wsplit<<<384, 256, 0, stream>>>(in_w_my, in_w_op, wbh, wbl);

  dim3 g2((N_CARDS + 127) / 128, 1536 / 128);
  proj_mfma<<<g2, 256, 0, stream>>>(embh, embl, wbh, wbl, in_b_my, in_b_op, proj);

  combine_w<<<dim3(256, 2), 256, 0, stream>>>(w1, out_w_my, out_w_op, wch, wcl);
  bias_kernel<<<1, 256, 0, stream>>>(w1, b1, out_b_my, out_b_op, bias_c);

  attn_kernel<<<BATCH, 256, 0, stream>>>(proj, my_decks, op_decks, adj,
                                         meanmy, meanop);

  gemm_ln_mfma<<<BATCH / 32, 256, 0, stream>>>(meanmy, meanop, wch, wcl, bias_c,
                                               ln_g, ln_b, meanmy);

  head_kernel<<<BATCH / 8, 256, 0, stream>>>(meanmy, w2, b2, w3, b3, out);
}

// Round 5
// 706.087 us; speedup vs baseline: 1.8571x; 1.0359x over previous
//
#include <hip/hip_runtime.h>
#include <hip/hip_bf16.h>
#include <hip/hip_fp16.h>
#include <math.h>

// Problem constants
#define N_CARDS 10000
#define HIDDEN  128
#define E       256
#define BATCH   16384
#define L       8
#define NH      4
#define HD      64

typedef __attribute__((ext_vector_type(8))) short short8;
typedef __attribute__((ext_vector_type(4))) float f32x4;
typedef unsigned short ust;

__device__ __forceinline__ f32x4 mfma16(short8 a, short8 b, f32x4 c) {
  return __builtin_amdgcn_mfma_f32_16x16x32_bf16(a, b, c, 0, 0, 0);
}
// split f32 -> hi bf16 (truncate) + lo bf16 (remainder); 3-term MFMA gives
// ~3e-5 relative error (al*bl term dropped).
__device__ __forceinline__ void split2(float x, ust& h, ust& l) {
  unsigned u = __float_as_uint(x);
  h = (ust)(u >> 16);
  float r = x - __uint_as_float(u & 0xFFFF0000u);
  l = (ust)(__float_as_uint(r) >> 16);
}

// ---------------------------------------------------------------------------
// K1: card embedding, pre-split into bf16 hi/lo planes.
// ---------------------------------------------------------------------------
__global__ __launch_bounds__(128) void emb_kernel(
    const float* __restrict__ xr, const float* __restrict__ xi,
    ust* __restrict__ embh, ust* __restrict__ embl) {
  int c = blockIdx.x;
  int d = threadIdx.x;
  float r  = xr[c * HIDDEN + d];
  float im = xi[c * HIDDEN + d];
  float amp = sqrtf(r * r + im * im + 1e-8f);
  float ph  = atan2f(im, r);
  ust h, l;
  split2(amp, h, l);
  embh[c * E + d] = h; embl[c * E + d] = l;
  split2(ph, h, l);
  embh[c * E + HIDDEN + d] = h; embl[c * E + HIDDEN + d] = l;
}

// ---------------------------------------------------------------------------
// K1b: split stacked projection weights [in_w_my; in_w_op] (1536x256) to
// bf16 hi/lo planes.
// ---------------------------------------------------------------------------
__global__ __launch_bounds__(256) void wsplit(
    const float* __restrict__ wmy, const float* __restrict__ wop,
    ust* __restrict__ wbh, ust* __restrict__ wbl) {
  int idx = blockIdx.x * 256 + threadIdx.x;
  int row = idx >> 6, c4 = idx & 63;
  const float* src = (row < 768) ? (wmy + (size_t)row * 256)
                                 : (wop + (size_t)(row - 768) * 256);
  float4 v = *(const float4*)(src + c4 * 4);
  ushort4 h, l;
  split2(v.x, h.x, l.x); split2(v.y, h.y, l.y);
  split2(v.z, h.z, l.z); split2(v.w, h.w, l.w);
  *(ushort4*)&wbh[(size_t)row * 256 + c4 * 4] = h;
  *(ushort4*)&wbl[(size_t)row * 256 + c4 * 4] = l;
}

// w2T[k][o] = w2[o][k]  (64 KB, one-time)
__global__ __launch_bounds__(256) void w2t_kernel(
    const float* __restrict__ w2, float* __restrict__ w2T) {
  int idx = blockIdx.x * 256 + threadIdx.x;  // 0..16383
  int k = idx >> 6, o = idx & 63;
  w2T[idx] = w2[o * 256 + k];
}

// ---------------------------------------------------------------------------
// K2: projection GEMM via split-bf16 MFMA; OUTPUT IN FP16 (only attn reads
// it; halves gather volume). 128x128 tile, BK=64, 4 waves 2x2, 4x4 MFMA.
// ---------------------------------------------------------------------------
#define PSTR 72
__global__ __launch_bounds__(256) void proj_mfma(
    const ust* __restrict__ embh, const ust* __restrict__ embl,
    const ust* __restrict__ wbh, const ust* __restrict__ wbl,
    const float* __restrict__ bmy, const float* __restrict__ bop,
    __half* __restrict__ proj) {
  __shared__ __align__(16) ust sAh[128 * PSTR];
  __shared__ __align__(16) ust sAl[128 * PSTR];
  __shared__ __align__(16) ust sBh[128 * PSTR];
  __shared__ __align__(16) ust sBl[128 * PSTR];
  int m0 = blockIdx.x * 128;
  int n0 = blockIdx.y * 128;
  int tid = threadIdx.x;
  int w = tid >> 6, lane = tid & 63;
  int wm = w >> 1, wn = w & 1;
  int lrow = lane & 15, lq = lane >> 4;

  f32x4 acc[4][4] = {};

  for (int kb = 0; kb < 256; kb += 64) {
#pragma unroll
    for (int rep = 0; rep < 4; ++rep) {
      int idx = rep * 256 + tid;
      int row = idx >> 3, ch = (idx & 7) * 8;
      int gm = m0 + row;
      short8 ah = {}, al = {};
      if (gm < N_CARDS) {
        ah = *(const short8*)&embh[(size_t)gm * 256 + kb + ch];
        al = *(const short8*)&embl[(size_t)gm * 256 + kb + ch];
      }
      *(short8*)&sAh[row * PSTR + ch] = ah;
      *(short8*)&sAl[row * PSTR + ch] = al;
      int gn = n0 + row;
      *(short8*)&sBh[row * PSTR + ch] = *(const short8*)&wbh[(size_t)gn * 256 + kb + ch];
      *(short8*)&sBl[row * PSTR + ch] = *(const short8*)&wbl[(size_t)gn * 256 + kb + ch];
    }
    __syncthreads();
#pragma unroll
    for (int ks = 0; ks < 2; ++ks) {
      int ko = ks * 32 + lq * 8;
      short8 ah[4], al[4], bh[4], bl[4];
#pragma unroll
      for (int i = 0; i < 4; ++i) {
        int ar = wm * 64 + i * 16 + lrow;
        ah[i] = *(const short8*)&sAh[ar * PSTR + ko];
        al[i] = *(const short8*)&sAl[ar * PSTR + ko];
        int br = wn * 64 + i * 16 + lrow;
        bh[i] = *(const short8*)&sBh[br * PSTR + ko];
        bl[i] = *(const short8*)&sBl[br * PSTR + ko];
      }
#pragma unroll
      for (int i = 0; i < 4; ++i)
#pragma unroll
        for (int j = 0; j < 4; ++j) {
          acc[i][j] = mfma16(ah[i], bh[j], acc[i][j]);
          acc[i][j] = mfma16(ah[i], bl[j], acc[i][j]);
          acc[i][j] = mfma16(al[i], bh[j], acc[i][j]);
        }
    }
    __syncthreads();
  }

  const float* bias = (n0 < 768) ? bmy : bop;
  int nbase = (n0 < 768) ? n0 : n0 - 768;
#pragma unroll
  for (int j = 0; j < 4; ++j) {
    int ncol = wn * 64 + j * 16 + lrow;
    float bv = bias[nbase + ncol];
#pragma unroll
    for (int i = 0; i < 4; ++i) {
      int mrow0 = m0 + wm * 64 + i * 16 + lq * 4;
#pragma unroll
      for (int r = 0; r < 4; ++r) {
        int m = mrow0 + r;
        if (m < N_CARDS)
          proj[(size_t)m * 1536 + n0 + ncol] = __float2half(acc[i][j][r] + bv);
      }
    }
  }
}

// ---------------------------------------------------------------------------
// K2b: Wcomb bf16 hi/lo planes [i][k], k in [0,512).
// ---------------------------------------------------------------------------
__global__ __launch_bounds__(256) void combine_w(
    const float* __restrict__ w1,
    const float* __restrict__ owmy, const float* __restrict__ owop,
    ust* __restrict__ wch, ust* __restrict__ wcl) {
  int i = blockIdx.x;
  int half = blockIdx.y;
  int kp = threadIdx.x;
  const float* ow = half ? owop : owmy;
  const float* w1r = w1 + (size_t)i * 512 + half * 256;
  float s = 0.f;
#pragma unroll 4
  for (int f = 0; f < 256; ++f) {
    s += w1r[f] * ow[(size_t)f * 256 + kp];
  }
  ust h, l;
  split2(s, h, l);
  wch[(size_t)i * 512 + half * 256 + kp] = h;
  wcl[(size_t)i * 512 + half * 256 + kp] = l;
}

// bias_c[i] = b1[i] + w1[i][:256]·out_b_my + w1[i][256:]·out_b_op
__global__ __launch_bounds__(256) void bias_kernel(
    const float* __restrict__ w1, const float* __restrict__ b1,
    const float* __restrict__ obm, const float* __restrict__ obo,
    float* __restrict__ bias_c) {
  int i = threadIdx.x;
  float s = b1[i];
  for (int f = 0; f < 256; f += 4) {
    float4 wa = *(const float4*)&w1[(size_t)i * 512 + f];
    float4 ba = *(const float4*)&obm[f];
    float4 wb = *(const float4*)&w1[(size_t)i * 512 + 256 + f];
    float4 bo = *(const float4*)&obo[f];
    s += wa.x * ba.x + wa.y * ba.y + wa.z * ba.z + wa.w * ba.w;
    s += wb.x * bo.x + wb.y * bo.y + wb.z * bo.z + wb.w * bo.w;
  }
  bias_c[i] = s;
}

// ---------------------------------------------------------------------------
// K3: per-batch attention. fp16 proj table. QK via LDS (f32, converted on
// stage); V read direct global->register in PV. Writes mean as bf16 hi/lo
// planes [b][512] (my=0:256, op=256:512) for the downstream MFMA GEMM.
// ---------------------------------------------------------------------------
#define ASTR 260
__global__ __launch_bounds__(256) void attn_kernel(
    const __half* __restrict__ proj,
    const int* __restrict__ my_decks, const int* __restrict__ op_decks,
    const int* __restrict__ adj,
    ust* __restrict__ meanh, ust* __restrict__ meanl) {
  __shared__ __align__(16) float tab[4 * 8 * ASTR];
  __shared__ int   cards[16];
  __shared__ float biasm[8][8];
  __shared__ float wbar[2][NH][8];

  int b = blockIdx.x;
  int tid = threadIdx.x;

  if (tid < 8)        cards[tid] = my_decks[b * L + tid];
  else if (tid < 16)  cards[tid] = op_decks[b * L + tid - 8];
  __syncthreads();

  // gather qmy(0,my), kmy(1,op), qop(3,op), kop(4,my) as f32 into LDS
#pragma unroll
  for (int it = 0; it < 4; ++it) {
    int idx = it * 256 + tid;        // 0..1023
    int t   = idx >> 8;              // 0..3
    int r   = (idx >> 5) & 7;
    int c8  = idx & 31;              // 8-half chunk
    int tp  = (t == 0) ? 0 : (t == 1) ? 1 : (t == 2) ? 3 : 4;
    int useMy = (t == 0) | (t == 3);
    int card  = cards[useMy ? r : (8 + r)];
    uint4 u = *(const uint4*)(proj + (size_t)card * 1536 + tp * 256 + c8 * 8);
    const __half* hp = (const __half*)&u;
    float4 f0 = make_float4(__half2float(hp[0]), __half2float(hp[1]),
                            __half2float(hp[2]), __half2float(hp[3]));
    float4 f1 = make_float4(__half2float(hp[4]), __half2float(hp[5]),
                            __half2float(hp[6]), __half2float(hp[7]));
    *(float4*)&tab[(t * 8 + r) * ASTR + c8 * 8]     = f0;
    *(float4*)&tab[(t * 8 + r) * ASTR + c8 * 8 + 4] = f1;
  }
  if (tid < 64) {
    int i = tid >> 3, j = tid & 7;
    int m = adj[(size_t)cards[i] * N_CARDS + cards[8 + j]];
    biasm[i][j] = (m > 0) ? 0.0f : -10000.0f;
  }
  __syncthreads();

  int w    = tid >> 6;
  int lane = tid & 63;
  int i = lane >> 3, j = lane & 7;
  {
    const float4* q4 = (const float4*)&tab[(0 * 8 + i) * ASTR + w * HD];
    const float4* k4 = (const float4*)&tab[(1 * 8 + j) * ASTR + w * HD];
    float s = 0.f;
#pragma unroll
    for (int d = 0; d < 16; ++d) {
      float4 a = q4[d], bb = k4[d];
      s += a.x * bb.x + a.y * bb.y + a.z * bb.z + a.w * bb.w;
    }
    s = s * 0.125f + biasm[i][j];
    float mx = s;
    mx = fmaxf(mx, __shfl_xor(mx, 1));
    mx = fmaxf(mx, __shfl_xor(mx, 2));
    mx = fmaxf(mx, __shfl_xor(mx, 4));
    float e = expf(s - mx);
    float sum = e;
    sum += __shfl_xor(sum, 1); sum += __shfl_xor(sum, 2); sum += __shfl_xor(sum, 4);
    float a = e / sum;
    a += __shfl_xor(a, 8); a += __shfl_xor(a, 16); a += __shfl_xor(a, 32);
    if (lane < 8) wbar[0][w][lane] = a * 0.125f;
  }
  {
    const float4* q4 = (const float4*)&tab[(2 * 8 + i) * ASTR + w * HD];
    const float4* k4 = (const float4*)&tab[(3 * 8 + j) * ASTR + w * HD];
    float s = 0.f;
#pragma unroll
    for (int d = 0; d < 16; ++d) {
      float4 a = q4[d], bb = k4[d];
      s += a.x * bb.x + a.y * bb.y + a.z * bb.z + a.w * bb.w;
    }
    s = s * 0.125f + biasm[j][i];
    float mx = s;
    mx = fmaxf(mx, __shfl_xor(mx, 1));
    mx = fmaxf(mx, __shfl_xor(mx, 2));
    mx = fmaxf(mx, __shfl_xor(mx, 4));
    float e = expf(s - mx);
    float sum = e;
    sum += __shfl_xor(sum, 1); sum += __shfl_xor(sum, 2); sum += __shfl_xor(sum, 4);
    float a = e / sum;
    a += __shfl_xor(a, 8); a += __shfl_xor(a, 16); a += __shfl_xor(a, 32);
    if (lane < 8) wbar[1][w][lane] = a * 0.125f;
  }
  __syncthreads();

  // PV: V rows read direct from global (coalesced across lanes)
  {
    int e = tid;
    int h = e >> 6;
    float sm = 0.f, so = 0.f;
#pragma unroll
    for (int jj = 0; jj < 8; ++jj) {
      float vm = __half2float(proj[(size_t)cards[8 + jj] * 1536 + 2 * 256 + e]);
      float vo = __half2float(proj[(size_t)cards[jj] * 1536 + 5 * 256 + e]);
      sm += wbar[0][h][jj] * vm;
      so += wbar[1][h][jj] * vo;
    }
    ust hh, ll;
    split2(sm, hh, ll);
    meanh[(size_t)b * 512 + e] = hh;
    meanl[(size_t)b * 512 + e] = ll;
    split2(so, hh, ll);
    meanh[(size_t)b * 512 + 256 + e] = hh;
    meanl[(size_t)b * 512 + 256 + e] = ll;
  }
}

// ---------------------------------------------------------------------------
// K4: fused h1 GEMM (split-bf16 MFMA) + bias + LN + ReLU + head MLP + logit.
// M=16384,N=256,K=512. Block tile 32x256, BK=32. h1 never leaves LDS.
// ---------------------------------------------------------------------------
#define GSTR 40
__global__ __launch_bounds__(256) void gemm_ln_head(
    const ust* __restrict__ meanh, const ust* __restrict__ meanl,
    const ust* __restrict__ wch, const ust* __restrict__ wcl,
    const float* __restrict__ bias_c,
    const float* __restrict__ ln_g, const float* __restrict__ ln_b,
    const float* __restrict__ w2T, const float* __restrict__ b2,
    const float* __restrict__ w3, const float* __restrict__ b3,
    float* __restrict__ out) {
  __shared__ __align__(16) char smem[46080];
  ust* sAh = (ust*)smem;
  ust* sAl = sAh + 32 * GSTR;
  ust* sBh = sAl + 32 * GSTR;
  ust* sBl = sBh + 256 * GSTR;
  float* h1s = (float*)smem;   // reused post-GEMM: 32 x 260 f32

  int m0 = blockIdx.x * 32;
  int tid = threadIdx.x;
  int w = tid >> 6, lane = tid & 63;
  int lrow = lane & 15, lq = lane >> 4;
  int cb = w * 64;

  f32x4 acc[2][4] = {};
  int ar = tid >> 3;
  int ak = (tid & 7) * 4;

  for (int it = 0; it < 16; ++it) {
    int kb = it * 32;
    *(uint2*)&sAh[ar * GSTR + ak] = *(const uint2*)&meanh[(size_t)(m0 + ar) * 512 + kb + ak];
    *(uint2*)&sAl[ar * GSTR + ak] = *(const uint2*)&meanl[(size_t)(m0 + ar) * 512 + kb + ak];
#pragma unroll
    for (int s = 0; s < 8; ++s) {
      int n = s * 32 + ar;
      *(uint2*)&sBh[n * GSTR + ak] = *(const uint2*)&wch[(size_t)n * 512 + kb + ak];
      *(uint2*)&sBl[n * GSTR + ak] = *(const uint2*)&wcl[(size_t)n * 512 + kb + ak];
    }
    __syncthreads();
    short8 ah[2], al[2];
#pragma unroll
    for (int t = 0; t < 2; ++t) {
      int r = t * 16 + lrow;
      ah[t] = *(const short8*)&sAh[r * GSTR + lq * 8];
      al[t] = *(const short8*)&sAl[r * GSTR + lq * 8];
    }
#pragma unroll
    for (int j = 0; j < 4; ++j) {
      int n = cb + j * 16 + lrow;
      short8 bh = *(const short8*)&sBh[n * GSTR + lq * 8];
      short8 bl = *(const short8*)&sBl[n * GSTR + lq * 8];
#pragma unroll
      for (int t = 0; t < 2; ++t) {
        acc[t][j] = mfma16(ah[t], bh, acc[t][j]);
        acc[t][j] = mfma16(ah[t], bl, acc[t][j]);
        acc[t][j] = mfma16(al[t], bh, acc[t][j]);
      }
    }
    __syncthreads();
  }

  // h1 (+bias) into LDS
#pragma unroll
  for (int t = 0; t < 2; ++t)
#pragma unroll
    for (int j = 0; j < 4; ++j) {
      int col = cb + j * 16 + lrow;
      float bv = bias_c[col];
#pragma unroll
      for (int r = 0; r < 4; ++r) {
        int row = t * 16 + lq * 4 + r;
        h1s[row * 260 + col] = acc[t][j][r] + bv;
      }
    }
  __syncthreads();

  // LN + ReLU in place (wave w owns rows w*8..w*8+7)
  float g[4], bb[4];
#pragma unroll
  for (int s = 0; s < 4; ++s) {
    g[s]  = ln_g[lane + s * 64];
    bb[s] = ln_b[lane + s * 64];
  }
  for (int q = 0; q < 8; ++q) {
    int row = w * 8 + q;
    float v[4]; float sum = 0.f, ss = 0.f;
#pragma unroll
    for (int s = 0; s < 4; ++s) {
      v[s] = h1s[row * 260 + lane + s * 64];
      sum += v[s]; ss += v[s] * v[s];
    }
    for (int m = 1; m < 64; m <<= 1) {
      sum += __shfl_xor(sum, m);
      ss  += __shfl_xor(ss, m);
    }
    float mu = sum * (1.f / 256.f);
    float rs = rsqrtf(ss * (1.f / 256.f) - mu * mu + 1e-5f);
#pragma unroll
    for (int s = 0; s < 4; ++s) {
      float o = fmaxf((v[s] - mu) * rs * g[s] + bb[s], 0.f);
      h1s[row * 260 + lane + s * 64] = o;
    }
  }
  __syncthreads();

  // head: thread = (o = lane, row group qg = wave). h2 then logit reduce.
  {
    int o = lane, qg = w;
    float hacc[8] = {};
    for (int k = 0; k < 256; k += 4) {
      float wv0 = w2T[(k + 0) * 64 + o];
      float wv1 = w2T[(k + 1) * 64 + o];
      float wv2 = w2T[(k + 2) * 64 + o];
      float wv3 = w2T[(k + 3) * 64 + o];
#pragma unroll
      for (int jj = 0; jj < 8; ++jj) {
        float4 hv = *(const float4*)&h1s[(qg * 8 + jj) * 260 + k];
        hacc[jj] += hv.x * wv0 + hv.y * wv1 + hv.z * wv2 + hv.w * wv3;
      }
    }
    float b2v = b2[o], w3v = w3[o], b3v = b3[0];
#pragma unroll
    for (int jj = 0; jj < 8; ++jj) {
      float v = fmaxf(hacc[jj] + b2v, 0.f) * w3v;
      v += __shfl_xor(v, 1);  v += __shfl_xor(v, 2);
      v += __shfl_xor(v, 4);  v += __shfl_xor(v, 8);
      v += __shfl_xor(v, 16); v += __shfl_xor(v, 32);
      if (o == 0) out[m0 + qg * 8 + jj] = v + b3v;
    }
  }
}

// ---------------------------------------------------------------------------
extern "C" void kernel_launch(void* const* d_in, const int* in_sizes, int n_in,
                              void* d_out, int out_size, void* d_ws, size_t ws_size,
                              hipStream_t stream) {
  const float* x_real   = (const float*)d_in[0];
  const float* x_imag   = (const float*)d_in[1];
  const int*   my_decks = (const int*)d_in[2];
  const int*   op_decks = (const int*)d_in[3];
  const int*   adj      = (const int*)d_in[4];
  const float* in_w_my  = (const float*)d_in[5];
  const float* in_b_my  = (const float*)d_in[6];
  const float* out_w_my = (const float*)d_in[7];
  const float* out_b_my = (const float*)d_in[8];
  const float* in_w_op  = (const float*)d_in[9];
  const float* in_b_op  = (const float*)d_in[10];
  const float* out_w_op = (const float*)d_in[11];
  const float* out_b_op = (const float*)d_in[12];
  const float* w1       = (const float*)d_in[13];
  const float* b1       = (const float*)d_in[14];
  const float* ln_g     = (const float*)d_in[15];
  const float* ln_b     = (const float*)d_in[16];
  const float* w2       = (const float*)d_in[17];
  const float* b2       = (const float*)d_in[18];
  const float* w3       = (const float*)d_in[19];
  const float* b3       = (const float*)d_in[20];

  __half* projh  = (__half*)d_ws;            // 10000*1536 halves
  ust* meanh     = (ust*)(projh + 15360000); // 16384*512
  ust* meanl     = meanh + 8388608;
  ust* wch       = meanl + 8388608;          // 256*512
  ust* wcl       = wch + 131072;
  ust* embh      = wcl + 131072;             // 10000*256
  ust* embl      = embh + 2560000;
  ust* wbh       = embl + 2560000;           // 1536*256
  ust* wbl       = wbh + 393216;
  float* bias_c  = (float*)(wbl + 393216);   // 256
  float* w2T     = bias_c + 256;             // 256*64
  float* out     = (float*)d_out;

  emb_kernel<<<N_CARDS, 128, 0, stream>>>(x_real, x_imag, embh, embl);
  wsplit<<<384, 256, 0, stream>>>(in_w_my, in_w_op, wbh, wbl);
  w2t_kernel<<<64, 256, 0, stream>>>(w2, w2T);

  dim3 g2((N_CARDS + 127) / 128, 1536 / 128);
  proj_mfma<<<g2, 256, 0, stream>>>(embh, embl, wbh, wbl, in_b_my, in_b_op, projh);

  combine_w<<<dim3(256, 2), 256, 0, stream>>>(w1, out_w_my, out_w_op, wch, wcl);
  bias_kernel<<<1, 256, 0, stream>>>(w1, b1, out_b_my, out_b_op, bias_c);

  attn_kernel<<<BATCH, 256, 0, stream>>>(projh, my_decks, op_decks, adj,
                                         meanh, meanl);

  gemm_ln_head<<<BATCH / 32, 256, 0, stream>>>(meanh, meanl, wch, wcl, bias_c,
                                               ln_g, ln_b, w2T, b2, w3, b3, out);
}

// Round 6
// 652.471 us; speedup vs baseline: 2.0097x; 1.0822x over previous
//
#include <hip/hip_runtime.h>
#include <hip/hip_bf16.h>
#include <hip/hip_fp16.h>
#include <math.h>

// Problem constants
#define N_CARDS 10000
#define HIDDEN  128
#define E       256
#define BATCH   16384
#define L       8
#define NH      4
#define HD      64

typedef __attribute__((ext_vector_type(8))) short short8;
typedef __attribute__((ext_vector_type(4))) float f32x4;
typedef _Float16 __attribute__((ext_vector_type(2))) h2v;
typedef unsigned short ust;

__device__ __forceinline__ f32x4 mfma16(short8 a, short8 b, f32x4 c) {
  return __builtin_amdgcn_mfma_f32_16x16x32_bf16(a, b, c, 0, 0, 0);
}
// split f32 -> hi bf16 (truncate) + lo bf16 (remainder); 3-term MFMA gives
// ~3e-5 relative error (al*bl term dropped).
__device__ __forceinline__ void split2(float x, ust& h, ust& l) {
  unsigned u = __float_as_uint(x);
  h = (ust)(u >> 16);
  float r = x - __uint_as_float(u & 0xFFFF0000u);
  l = (ust)(__float_as_uint(r) >> 16);
}

// fp16 dot over 64 dims, f32 accumulate (v_dot2_f32_f16 when available)
__device__ __forceinline__ float dot64(const __half* q, const __half* k) {
  float s = 0.f;
#pragma unroll
  for (int d = 0; d < 8; ++d) {
    short8 qa = *(const short8*)(q + d * 8);
    short8 kb = *(const short8*)(k + d * 8);
    const h2v* q2 = (const h2v*)&qa;
    const h2v* k2 = (const h2v*)&kb;
#pragma unroll
    for (int m = 0; m < 4; ++m) {
#if __has_builtin(__builtin_amdgcn_fdot2)
      s = __builtin_amdgcn_fdot2(q2[m], k2[m], s, false);
#else
      s += (float)q2[m][0] * (float)k2[m][0] + (float)q2[m][1] * (float)k2[m][1];
#endif
    }
  }
  return s;
}

// ---------------------------------------------------------------------------
// K1: fused prep: emb split (blocks 0..4999), in_w split (5000..5383),
// w2 transpose (5384..5447).
// ---------------------------------------------------------------------------
__global__ __launch_bounds__(256) void prep_all(
    const float* __restrict__ xr, const float* __restrict__ xi,
    const float* __restrict__ wmy, const float* __restrict__ wop,
    const float* __restrict__ w2,
    ust* __restrict__ embh, ust* __restrict__ embl,
    ust* __restrict__ wbh, ust* __restrict__ wbl,
    float* __restrict__ w2T) {
  int bid = blockIdx.x;
  int tid = threadIdx.x;
  if (bid < 5000) {
    int c = bid * 2 + (tid >> 7);
    int d = tid & 127;
    float r  = xr[c * HIDDEN + d];
    float im = xi[c * HIDDEN + d];
    float amp = sqrtf(r * r + im * im + 1e-8f);
    float ph  = atan2f(im, r);
    ust h, l;
    split2(amp, h, l);
    embh[c * E + d] = h; embl[c * E + d] = l;
    split2(ph, h, l);
    embh[c * E + HIDDEN + d] = h; embl[c * E + HIDDEN + d] = l;
  } else if (bid < 5384) {
    int idx = (bid - 5000) * 256 + tid;
    int row = idx >> 6, c4 = idx & 63;
    const float* src = (row < 768) ? (wmy + (size_t)row * 256)
                                   : (wop + (size_t)(row - 768) * 256);
    float4 v = *(const float4*)(src + c4 * 4);
    ushort4 h, l;
    split2(v.x, h.x, l.x); split2(v.y, h.y, l.y);
    split2(v.z, h.z, l.z); split2(v.w, h.w, l.w);
    *(ushort4*)&wbh[(size_t)row * 256 + c4 * 4] = h;
    *(ushort4*)&wbl[(size_t)row * 256 + c4 * 4] = l;
  } else {
    int idx = (bid - 5384) * 256 + tid;
    int k = idx >> 6, o = idx & 63;
    w2T[idx] = w2[o * 256 + k];
  }
}

// ---------------------------------------------------------------------------
// K2: projection GEMM via split-bf16 MFMA; OUTPUT FP16.
// 128x128 tile, BK=64, 4 waves 2x2, 4x4 MFMA.
// ---------------------------------------------------------------------------
#define PSTR 72
__global__ __launch_bounds__(256) void proj_mfma(
    const ust* __restrict__ embh, const ust* __restrict__ embl,
    const ust* __restrict__ wbh, const ust* __restrict__ wbl,
    const float* __restrict__ bmy, const float* __restrict__ bop,
    __half* __restrict__ proj) {
  __shared__ __align__(16) ust sAh[128 * PSTR];
  __shared__ __align__(16) ust sAl[128 * PSTR];
  __shared__ __align__(16) ust sBh[128 * PSTR];
  __shared__ __align__(16) ust sBl[128 * PSTR];
  int m0 = blockIdx.x * 128;
  int n0 = blockIdx.y * 128;
  int tid = threadIdx.x;
  int w = tid >> 6, lane = tid & 63;
  int wm = w >> 1, wn = w & 1;
  int lrow = lane & 15, lq = lane >> 4;

  f32x4 acc[4][4] = {};

  for (int kb = 0; kb < 256; kb += 64) {
#pragma unroll
    for (int rep = 0; rep < 4; ++rep) {
      int idx = rep * 256 + tid;
      int row = idx >> 3, ch = (idx & 7) * 8;
      int gm = m0 + row;
      short8 ah = {}, al = {};
      if (gm < N_CARDS) {
        ah = *(const short8*)&embh[(size_t)gm * 256 + kb + ch];
        al = *(const short8*)&embl[(size_t)gm * 256 + kb + ch];
      }
      *(short8*)&sAh[row * PSTR + ch] = ah;
      *(short8*)&sAl[row * PSTR + ch] = al;
      int gn = n0 + row;
      *(short8*)&sBh[row * PSTR + ch] = *(const short8*)&wbh[(size_t)gn * 256 + kb + ch];
      *(short8*)&sBl[row * PSTR + ch] = *(const short8*)&wbl[(size_t)gn * 256 + kb + ch];
    }
    __syncthreads();
#pragma unroll
    for (int ks = 0; ks < 2; ++ks) {
      int ko = ks * 32 + lq * 8;
      short8 ah[4], al[4], bh[4], bl[4];
#pragma unroll
      for (int i = 0; i < 4; ++i) {
        int ar = wm * 64 + i * 16 + lrow;
        ah[i] = *(const short8*)&sAh[ar * PSTR + ko];
        al[i] = *(const short8*)&sAl[ar * PSTR + ko];
        int br = wn * 64 + i * 16 + lrow;
        bh[i] = *(const short8*)&sBh[br * PSTR + ko];
        bl[i] = *(const short8*)&sBl[br * PSTR + ko];
      }
#pragma unroll
      for (int i = 0; i < 4; ++i)
#pragma unroll
        for (int j = 0; j < 4; ++j) {
          acc[i][j] = mfma16(ah[i], bh[j], acc[i][j]);
          acc[i][j] = mfma16(ah[i], bl[j], acc[i][j]);
          acc[i][j] = mfma16(al[i], bh[j], acc[i][j]);
        }
    }
    __syncthreads();
  }

  const float* bias = (n0 < 768) ? bmy : bop;
  int nbase = (n0 < 768) ? n0 : n0 - 768;
#pragma unroll
  for (int j = 0; j < 4; ++j) {
    int ncol = wn * 64 + j * 16 + lrow;
    float bv = bias[nbase + ncol];
#pragma unroll
    for (int i = 0; i < 4; ++i) {
      int mrow0 = m0 + wm * 64 + i * 16 + lq * 4;
#pragma unroll
      for (int r = 0; r < 4; ++r) {
        int m = mrow0 + r;
        if (m < N_CARDS)
          proj[(size_t)m * 1536 + n0 + ncol] = __float2half(acc[i][j][r] + bv);
      }
    }
  }
}

// ---------------------------------------------------------------------------
// K2b: Wcomb bf16 hi/lo planes [i][k] (k in [0,512)); bias_c fused in
// (blockIdx.x == 256 row).
// ---------------------------------------------------------------------------
__global__ __launch_bounds__(256) void combine_w(
    const float* __restrict__ w1, const float* __restrict__ b1,
    const float* __restrict__ owmy, const float* __restrict__ owop,
    const float* __restrict__ obm, const float* __restrict__ obo,
    ust* __restrict__ wch, ust* __restrict__ wcl,
    float* __restrict__ bias_c) {
  int i = blockIdx.x;
  int half = blockIdx.y;
  if (i == 256) {
    if (half) return;
    int t = threadIdx.x;
    float s = b1[t];
    for (int f = 0; f < 256; f += 4) {
      float4 wa = *(const float4*)&w1[(size_t)t * 512 + f];
      float4 ba = *(const float4*)&obm[f];
      float4 wb = *(const float4*)&w1[(size_t)t * 512 + 256 + f];
      float4 bo = *(const float4*)&obo[f];
      s += wa.x * ba.x + wa.y * ba.y + wa.z * ba.z + wa.w * ba.w;
      s += wb.x * bo.x + wb.y * bo.y + wb.z * bo.z + wb.w * bo.w;
    }
    bias_c[t] = s;
    return;
  }
  int kp = threadIdx.x;
  const float* ow = half ? owop : owmy;
  const float* w1r = w1 + (size_t)i * 512 + half * 256;
  float s = 0.f;
#pragma unroll 4
  for (int f = 0; f < 256; ++f) {
    s += w1r[f] * ow[(size_t)f * 256 + kp];
  }
  ust h, l;
  split2(s, h, l);
  wch[(size_t)i * 512 + half * 256 + kp] = h;
  wcl[(size_t)i * 512 + half * 256 + kp] = l;
}

// ---------------------------------------------------------------------------
// K3: per-batch attention v3. fp16 Q/K in LDS (17 KB -> 8 blocks/CU),
// scores via v_dot2_f32_f16; V via __half2 direct-global; paired stores.
// ---------------------------------------------------------------------------
#define AST 264
__global__ __launch_bounds__(256) void attn_kernel(
    const __half* __restrict__ proj,
    const int* __restrict__ my_decks, const int* __restrict__ op_decks,
    const int* __restrict__ adj,
    ust* __restrict__ meanh, ust* __restrict__ meanl) {
  __shared__ __align__(16) __half tab[4 * 8 * AST];
  __shared__ int   cards[16];
  __shared__ float biasm[8][8];
  __shared__ float wbar[2][NH][8];

  int b = blockIdx.x;
  int tid = threadIdx.x;

  if (tid < 8)        cards[tid] = my_decks[b * L + tid];
  else if (tid < 16)  cards[tid] = op_decks[b * L + tid - 8];
  __syncthreads();

  // gather qmy(0,my), kmy(1,op), qop(3,op), kop(4,my) fp16 into LDS
#pragma unroll
  for (int it = 0; it < 4; ++it) {
    int idx = it * 256 + tid;        // 0..1023 chunks of 8 halves
    int t   = idx >> 8;
    int r   = (idx >> 5) & 7;
    int c8  = idx & 31;
    int tp  = (t == 0) ? 0 : (t == 1) ? 1 : (t == 2) ? 3 : 4;
    int useMy = (t == 0) | (t == 3);
    int card  = cards[useMy ? r : (8 + r)];
    uint4 u = *(const uint4*)(proj + (size_t)card * 1536 + tp * 256 + c8 * 8);
    *(uint4*)&tab[(t * 8 + r) * AST + c8 * 8] = u;
  }
  if (tid < 64) {
    int i = tid >> 3, j = tid & 7;
    int m = adj[(size_t)cards[i] * N_CARDS + cards[8 + j]];
    biasm[i][j] = (m > 0) ? 0.0f : -10000.0f;
  }
  __syncthreads();

  int w    = tid >> 6;
  int lane = tid & 63;
  int i = lane >> 3, j = lane & 7;
  {
    float s = dot64(&tab[(0 * 8 + i) * AST + w * HD],
                    &tab[(1 * 8 + j) * AST + w * HD]);
    s = s * 0.125f + biasm[i][j];
    float mx = s;
    mx = fmaxf(mx, __shfl_xor(mx, 1));
    mx = fmaxf(mx, __shfl_xor(mx, 2));
    mx = fmaxf(mx, __shfl_xor(mx, 4));
    float e = expf(s - mx);
    float sum = e;
    sum += __shfl_xor(sum, 1); sum += __shfl_xor(sum, 2); sum += __shfl_xor(sum, 4);
    float a = e / sum;
    a += __shfl_xor(a, 8); a += __shfl_xor(a, 16); a += __shfl_xor(a, 32);
    if (lane < 8) wbar[0][w][lane] = a * 0.125f;
  }
  {
    float s = dot64(&tab[(2 * 8 + i) * AST + w * HD],
                    &tab[(3 * 8 + j) * AST + w * HD]);
    s = s * 0.125f + biasm[j][i];
    float mx = s;
    mx = fmaxf(mx, __shfl_xor(mx, 1));
    mx = fmaxf(mx, __shfl_xor(mx, 2));
    mx = fmaxf(mx, __shfl_xor(mx, 4));
    float e = expf(s - mx);
    float sum = e;
    sum += __shfl_xor(sum, 1); sum += __shfl_xor(sum, 2); sum += __shfl_xor(sum, 4);
    float a = e / sum;
    a += __shfl_xor(a, 8); a += __shfl_xor(a, 16); a += __shfl_xor(a, 32);
    if (lane < 8) wbar[1][w][lane] = a * 0.125f;
  }
  __syncthreads();

  // PV: thread = (side, pair p): side 0 -> mean_my (v from op cards, blk 2),
  // side 1 -> mean_op (v from my cards, blk 5). half2 loads, paired stores.
  {
    int p = tid & 127, side = tid >> 7;
    int h = p >> 5;   // head of elements 2p, 2p+1
    int tp = side ? 5 : 2;
    float s0 = 0.f, s1 = 0.f;
#pragma unroll
    for (int jj = 0; jj < 8; ++jj) {
      int card = cards[side ? jj : (8 + jj)];
      __half2 v2 = *(const __half2*)(proj + (size_t)card * 1536 + tp * 256 + p * 2);
      float2 vf = __half22float2(v2);
      float wv = wbar[side][h][jj];
      s0 += wv * vf.x;
      s1 += wv * vf.y;
    }
    ust h0, l0, h1, l1;
    split2(s0, h0, l0);
    split2(s1, h1, l1);
    unsigned hh = (unsigned)h0 | ((unsigned)h1 << 16);
    unsigned ll = (unsigned)l0 | ((unsigned)l1 << 16);
    *(unsigned*)&meanh[(size_t)b * 512 + side * 256 + p * 2] = hh;
    *(unsigned*)&meanl[(size_t)b * 512 + side * 256 + p * 2] = ll;
  }
}

// ---------------------------------------------------------------------------
// K4: fused h1 GEMM (split-bf16 MFMA) + bias + LN + ReLU + head MLP + logit.
// ---------------------------------------------------------------------------
#define GSTR 40
__global__ __launch_bounds__(256) void gemm_ln_head(
    const ust* __restrict__ meanh, const ust* __restrict__ meanl,
    const ust* __restrict__ wch, const ust* __restrict__ wcl,
    const float* __restrict__ bias_c,
    const float* __restrict__ ln_g, const float* __restrict__ ln_b,
    const float* __restrict__ w2T, const float* __restrict__ b2,
    const float* __restrict__ w3, const float* __restrict__ b3,
    float* __restrict__ out) {
  __shared__ __align__(16) char smem[46080];
  ust* sAh = (ust*)smem;
  ust* sAl = sAh + 32 * GSTR;
  ust* sBh = sAl + 32 * GSTR;
  ust* sBl = sBh + 256 * GSTR;
  float* h1s = (float*)smem;   // reused post-GEMM: 32 x 260 f32

  int m0 = blockIdx.x * 32;
  int tid = threadIdx.x;
  int w = tid >> 6, lane = tid & 63;
  int lrow = lane & 15, lq = lane >> 4;
  int cb = w * 64;

  f32x4 acc[2][4] = {};
  int ar = tid >> 3;
  int ak = (tid & 7) * 4;

  for (int it = 0; it < 16; ++it) {
    int kb = it * 32;
    *(uint2*)&sAh[ar * GSTR + ak] = *(const uint2*)&meanh[(size_t)(m0 + ar) * 512 + kb + ak];
    *(uint2*)&sAl[ar * GSTR + ak] = *(const uint2*)&meanl[(size_t)(m0 + ar) * 512 + kb + ak];
#pragma unroll
    for (int s = 0; s < 8; ++s) {
      int n = s * 32 + ar;
      *(uint2*)&sBh[n * GSTR + ak] = *(const uint2*)&wch[(size_t)n * 512 + kb + ak];
      *(uint2*)&sBl[n * GSTR + ak] = *(const uint2*)&wcl[(size_t)n * 512 + kb + ak];
    }
    __syncthreads();
    short8 ah[2], al[2];
#pragma unroll
    for (int t = 0; t < 2; ++t) {
      int r = t * 16 + lrow;
      ah[t] = *(const short8*)&sAh[r * GSTR + lq * 8];
      al[t] = *(const short8*)&sAl[r * GSTR + lq * 8];
    }
#pragma unroll
    for (int j = 0; j < 4; ++j) {
      int n = cb + j * 16 + lrow;
      short8 bh = *(const short8*)&sBh[n * GSTR + lq * 8];
      short8 bl = *(const short8*)&sBl[n * GSTR + lq * 8];
#pragma unroll
      for (int t = 0; t < 2; ++t) {
        acc[t][j] = mfma16(ah[t], bh, acc[t][j]);
        acc[t][j] = mfma16(ah[t], bl, acc[t][j]);
        acc[t][j] = mfma16(al[t], bh, acc[t][j]);
      }
    }
    __syncthreads();
  }

#pragma unroll
  for (int t = 0; t < 2; ++t)
#pragma unroll
    for (int j = 0; j < 4; ++j) {
      int col = cb + j * 16 + lrow;
      float bv = bias_c[col];
#pragma unroll
      for (int r = 0; r < 4; ++r) {
        int row = t * 16 + lq * 4 + r;
        h1s[row * 260 + col] = acc[t][j][r] + bv;
      }
    }
  __syncthreads();

  float g[4], bb[4];
#pragma unroll
  for (int s = 0; s < 4; ++s) {
    g[s]  = ln_g[lane + s * 64];
    bb[s] = ln_b[lane + s * 64];
  }
  for (int q = 0; q < 8; ++q) {
    int row = w * 8 + q;
    float v[4]; float sum = 0.f, ss = 0.f;
#pragma unroll
    for (int s = 0; s < 4; ++s) {
      v[s] = h1s[row * 260 + lane + s * 64];
      sum += v[s]; ss += v[s] * v[s];
    }
    for (int m = 1; m < 64; m <<= 1) {
      sum += __shfl_xor(sum, m);
      ss  += __shfl_xor(ss, m);
    }
    float mu = sum * (1.f / 256.f);
    float rs = rsqrtf(ss * (1.f / 256.f) - mu * mu + 1e-5f);
#pragma unroll
    for (int s = 0; s < 4; ++s) {
      float o = fmaxf((v[s] - mu) * rs * g[s] + bb[s], 0.f);
      h1s[row * 260 + lane + s * 64] = o;
    }
  }
  __syncthreads();

  {
    int o = lane, qg = w;
    float hacc[8] = {};
    for (int k = 0; k < 256; k += 4) {
      float wv0 = w2T[(k + 0) * 64 + o];
      float wv1 = w2T[(k + 1) * 64 + o];
      float wv2 = w2T[(k + 2) * 64 + o];
      float wv3 = w2T[(k + 3) * 64 + o];
#pragma unroll
      for (int jj = 0; jj < 8; ++jj) {
        float4 hv = *(const float4*)&h1s[(qg * 8 + jj) * 260 + k];
        hacc[jj] += hv.x * wv0 + hv.y * wv1 + hv.z * wv2 + hv.w * wv3;
      }
    }
    float b2v = b2[o], w3v = w3[o], b3v = b3[0];
#pragma unroll
    for (int jj = 0; jj < 8; ++jj) {
      float v = fmaxf(hacc[jj] + b2v, 0.f) * w3v;
      v += __shfl_xor(v, 1);  v += __shfl_xor(v, 2);
      v += __shfl_xor(v, 4);  v += __shfl_xor(v, 8);
      v += __shfl_xor(v, 16); v += __shfl_xor(v, 32);
      if (o == 0) out[m0 + qg * 8 + jj] = v + b3v;
    }
  }
}

// ---------------------------------------------------------------------------
extern "C" void kernel_launch(void* const* d_in, const int* in_sizes, int n_in,
                              void* d_out, int out_size, void* d_ws, size_t ws_size,
                              hipStream_t stream) {
  const float* x_real   = (const float*)d_in[0];
  const float* x_imag   = (const float*)d_in[1];
  const int*   my_decks = (const int*)d_in[2];
  const int*   op_decks = (const int*)d_in[3];
  const int*   adj      = (const int*)d_in[4];
  const float* in_w_my  = (const float*)d_in[5];
  const float* in_b_my  = (const float*)d_in[6];
  const float* out_w_my = (const float*)d_in[7];
  const float* out_b_my = (const float*)d_in[8];
  const float* in_w_op  = (const float*)d_in[9];
  const float* in_b_op  = (const float*)d_in[10];
  const float* out_w_op = (const float*)d_in[11];
  const float* out_b_op = (const float*)d_in[12];
  const float* w1       = (const float*)d_in[13];
  const float* b1       = (const float*)d_in[14];
  const float* ln_g     = (const float*)d_in[15];
  const float* ln_b     = (const float*)d_in[16];
  const float* w2       = (const float*)d_in[17];
  const float* b2       = (const float*)d_in[18];
  const float* w3       = (const float*)d_in[19];
  const float* b3       = (const float*)d_in[20];

  __half* projh  = (__half*)d_ws;            // 10000*1536 halves
  ust* meanh     = (ust*)(projh + 15360000); // 16384*512
  ust* meanl     = meanh + 8388608;
  ust* wch       = meanl + 8388608;          // 256*512
  ust* wcl       = wch + 131072;
  ust* embh      = wcl + 131072;             // 10000*256
  ust* embl      = embh + 2560000;
  ust* wbh       = embl + 2560000;           // 1536*256
  ust* wbl       = wbh + 393216;
  float* bias_c  = (float*)(wbl + 393216);   // 256
  float* w2T     = bias_c + 256;             // 256*64
  float* out     = (float*)d_out;

  prep_all<<<5448, 256, 0, stream>>>(x_real, x_imag, in_w_my, in_w_op, w2,
                                     embh, embl, wbh, wbl, w2T);

  dim3 g2((N_CARDS + 127) / 128, 1536 / 128);
  proj_mfma<<<g2, 256, 0, stream>>>(embh, embl, wbh, wbl, in_b_my, in_b_op, projh);

  combine_w<<<dim3(257, 2), 256, 0, stream>>>(w1, b1, out_w_my, out_w_op,
                                              out_b_my, out_b_op, wch, wcl, bias_c);

  attn_kernel<<<BATCH, 256, 0, stream>>>(projh, my_decks, op_decks, adj,
                                         meanh, meanl);

  gemm_ln_head<<<BATCH / 32, 256, 0, stream>>>(meanh, meanl, wch, wcl, bias_c,
                                               ln_g, ln_b, w2T, b2, w3, b3, out);
}

// Round 7
// 628.081 us; speedup vs baseline: 2.0878x; 1.0388x over previous
//
#include <hip/hip_runtime.h>
#include <hip/hip_bf16.h>
#include <hip/hip_fp16.h>
#include <math.h>

// Problem constants
#define N_CARDS 10000
#define HIDDEN  128
#define E       256
#define BATCH   16384
#define L       8
#define NH      4
#define HD      64

typedef __attribute__((ext_vector_type(8))) short short8;
typedef __attribute__((ext_vector_type(4))) float f32x4;
typedef _Float16 __attribute__((ext_vector_type(8))) half8;
typedef _Float16 __attribute__((ext_vector_type(2))) h2v;
typedef unsigned short ust;

__device__ __forceinline__ f32x4 mfmaf16(half8 a, half8 b, f32x4 c) {
  return __builtin_amdgcn_mfma_f32_16x16x32_f16(a, b, c, 0, 0, 0);
}

// fp16 dot over 64 dims, f32 accumulate (v_dot2_f32_f16 when available)
__device__ __forceinline__ float dot64(const __half* q, const __half* k) {
  float s = 0.f;
#pragma unroll
  for (int d = 0; d < 8; ++d) {
    short8 qa = *(const short8*)(q + d * 8);
    short8 kb = *(const short8*)(k + d * 8);
    const h2v* q2 = (const h2v*)&qa;
    const h2v* k2 = (const h2v*)&kb;
#pragma unroll
    for (int m = 0; m < 4; ++m) {
#if __has_builtin(__builtin_amdgcn_fdot2)
      s = __builtin_amdgcn_fdot2(q2[m], k2[m], s, false);
#else
      s += (float)q2[m][0] * (float)k2[m][0] + (float)q2[m][1] * (float)k2[m][1];
#endif
    }
  }
  return s;
}

// ---------------------------------------------------------------------------
// K1: fused prep: emb->fp16 (blocks 0..4999), in_w->fp16 (5000..5383),
// w2 transpose (5384..5447).
// ---------------------------------------------------------------------------
__global__ __launch_bounds__(256) void prep_all(
    const float* __restrict__ xr, const float* __restrict__ xi,
    const float* __restrict__ wmy, const float* __restrict__ wop,
    const float* __restrict__ w2,
    __half* __restrict__ embf, __half* __restrict__ wbf,
    float* __restrict__ w2T) {
  int bid = blockIdx.x;
  int tid = threadIdx.x;
  if (bid < 5000) {
    int c = bid * 2 + (tid >> 7);
    int d = tid & 127;
    float r  = xr[c * HIDDEN + d];
    float im = xi[c * HIDDEN + d];
    float amp = sqrtf(r * r + im * im + 1e-8f);
    float ph  = atan2f(im, r);
    embf[c * E + d]          = __float2half(amp);
    embf[c * E + HIDDEN + d] = __float2half(ph);
  } else if (bid < 5384) {
    int idx = (bid - 5000) * 256 + tid;   // float4 over 1536*256/4
    int row = idx >> 6, c4 = idx & 63;
    const float* src = (row < 768) ? (wmy + (size_t)row * 256)
                                   : (wop + (size_t)(row - 768) * 256);
    float4 v = *(const float4*)(src + c4 * 4);
    __half h[4] = {__float2half(v.x), __float2half(v.y),
                   __float2half(v.z), __float2half(v.w)};
    *(uint2*)&wbf[(size_t)row * 256 + c4 * 4] = *(const uint2*)h;
  } else {
    int idx = (bid - 5384) * 256 + tid;
    int k = idx >> 6, o = idx & 63;
    w2T[idx] = w2[o * 256 + k];
  }
}

// ---------------------------------------------------------------------------
// K2: projection GEMM, pure fp16 MFMA (f32 accumulate); OUTPUT FP16.
// 128x128 tile, BK=64, 4 waves 2x2, 4x4 MFMA. LDS 36 KB -> 4 blocks/CU.
// ---------------------------------------------------------------------------
#define PSTR 72
__global__ __launch_bounds__(256) void proj_mfma(
    const __half* __restrict__ embf, const __half* __restrict__ wbf,
    const float* __restrict__ bmy, const float* __restrict__ bop,
    __half* __restrict__ proj) {
  __shared__ __align__(16) __half sA[128 * PSTR];
  __shared__ __align__(16) __half sB[128 * PSTR];
  int m0 = blockIdx.x * 128;
  int n0 = blockIdx.y * 128;
  int tid = threadIdx.x;
  int w = tid >> 6, lane = tid & 63;
  int wm = w >> 1, wn = w & 1;
  int lrow = lane & 15, lq = lane >> 4;

  f32x4 acc[4][4] = {};

  for (int kb = 0; kb < 256; kb += 64) {
#pragma unroll
    for (int rep = 0; rep < 4; ++rep) {
      int idx = rep * 256 + tid;       // 0..1023
      int row = idx >> 3, ch = (idx & 7) * 8;
      int gm = m0 + row;
      half8 av = {};
      if (gm < N_CARDS) av = *(const half8*)&embf[(size_t)gm * 256 + kb + ch];
      *(half8*)&sA[row * PSTR + ch] = av;
      int gn = n0 + row;
      *(half8*)&sB[row * PSTR + ch] = *(const half8*)&wbf[(size_t)gn * 256 + kb + ch];
    }
    __syncthreads();
#pragma unroll
    for (int ks = 0; ks < 2; ++ks) {
      int ko = ks * 32 + lq * 8;
      half8 a[4], b[4];
#pragma unroll
      for (int i = 0; i < 4; ++i) {
        a[i] = *(const half8*)&sA[(wm * 64 + i * 16 + lrow) * PSTR + ko];
        b[i] = *(const half8*)&sB[(wn * 64 + i * 16 + lrow) * PSTR + ko];
      }
#pragma unroll
      for (int i = 0; i < 4; ++i)
#pragma unroll
        for (int j = 0; j < 4; ++j)
          acc[i][j] = mfmaf16(a[i], b[j], acc[i][j]);
    }
    __syncthreads();
  }

  const float* bias = (n0 < 768) ? bmy : bop;
  int nbase = (n0 < 768) ? n0 : n0 - 768;
#pragma unroll
  for (int j = 0; j < 4; ++j) {
    int ncol = wn * 64 + j * 16 + lrow;
    float bv = bias[nbase + ncol];
#pragma unroll
    for (int i = 0; i < 4; ++i) {
      int mrow0 = m0 + wm * 64 + i * 16 + lq * 4;
#pragma unroll
      for (int r = 0; r < 4; ++r) {
        int m = mrow0 + r;
        if (m < N_CARDS)
          proj[(size_t)m * 1536 + n0 + ncol] = __float2half(acc[i][j][r] + bv);
      }
    }
  }
}

// ---------------------------------------------------------------------------
// K2b: Wcomb fp16 [i][k] (k in [0,512)); bias_c fused (blockIdx.x == 256).
// ---------------------------------------------------------------------------
__global__ __launch_bounds__(256) void combine_w(
    const float* __restrict__ w1, const float* __restrict__ b1,
    const float* __restrict__ owmy, const float* __restrict__ owop,
    const float* __restrict__ obm, const float* __restrict__ obo,
    __half* __restrict__ wcf, float* __restrict__ bias_c) {
  int i = blockIdx.x;
  int half_ = blockIdx.y;
  if (i == 256) {
    if (half_) return;
    int t = threadIdx.x;
    float s = b1[t];
    for (int f = 0; f < 256; f += 4) {
      float4 wa = *(const float4*)&w1[(size_t)t * 512 + f];
      float4 ba = *(const float4*)&obm[f];
      float4 wb = *(const float4*)&w1[(size_t)t * 512 + 256 + f];
      float4 bo = *(const float4*)&obo[f];
      s += wa.x * ba.x + wa.y * ba.y + wa.z * ba.z + wa.w * ba.w;
      s += wb.x * bo.x + wb.y * bo.y + wb.z * bo.z + wb.w * bo.w;
    }
    bias_c[t] = s;
    return;
  }
  int kp = threadIdx.x;
  const float* ow = half_ ? owop : owmy;
  const float* w1r = w1 + (size_t)i * 512 + half_ * 256;
  float s = 0.f;
#pragma unroll 4
  for (int f = 0; f < 256; ++f) {
    s += w1r[f] * ow[(size_t)f * 256 + kp];
  }
  wcf[(size_t)i * 512 + half_ * 256 + kp] = __float2half(s);
}

// ---------------------------------------------------------------------------
// K3: per-batch attention. fp16 Q/K in LDS (17 KB -> 8 blocks/CU),
// scores via v_dot2_f32_f16; V via __half2 direct-global; mean stored fp16.
// ---------------------------------------------------------------------------
#define AST 264
__global__ __launch_bounds__(256) void attn_kernel(
    const __half* __restrict__ proj,
    const int* __restrict__ my_decks, const int* __restrict__ op_decks,
    const int* __restrict__ adj,
    __half* __restrict__ meanf) {
  __shared__ __align__(16) __half tab[4 * 8 * AST];
  __shared__ int   cards[16];
  __shared__ float biasm[8][8];
  __shared__ float wbar[2][NH][8];

  int b = blockIdx.x;
  int tid = threadIdx.x;

  if (tid < 8)        cards[tid] = my_decks[b * L + tid];
  else if (tid < 16)  cards[tid] = op_decks[b * L + tid - 8];
  __syncthreads();

  // gather qmy(0,my), kmy(1,op), qop(3,op), kop(4,my) fp16 into LDS
#pragma unroll
  for (int it = 0; it < 4; ++it) {
    int idx = it * 256 + tid;        // 0..1023 chunks of 8 halves
    int t   = idx >> 8;
    int r   = (idx >> 5) & 7;
    int c8  = idx & 31;
    int tp  = (t == 0) ? 0 : (t == 1) ? 1 : (t == 2) ? 3 : 4;
    int useMy = (t == 0) | (t == 3);
    int card  = cards[useMy ? r : (8 + r)];
    uint4 u = *(const uint4*)(proj + (size_t)card * 1536 + tp * 256 + c8 * 8);
    *(uint4*)&tab[(t * 8 + r) * AST + c8 * 8] = u;
  }
  if (tid < 64) {
    int i = tid >> 3, j = tid & 7;
    int m = adj[(size_t)cards[i] * N_CARDS + cards[8 + j]];
    biasm[i][j] = (m > 0) ? 0.0f : -10000.0f;
  }
  __syncthreads();

  int w    = tid >> 6;
  int lane = tid & 63;
  int i = lane >> 3, j = lane & 7;
  {
    float s = dot64(&tab[(0 * 8 + i) * AST + w * HD],
                    &tab[(1 * 8 + j) * AST + w * HD]);
    s = s * 0.125f + biasm[i][j];
    float mx = s;
    mx = fmaxf(mx, __shfl_xor(mx, 1));
    mx = fmaxf(mx, __shfl_xor(mx, 2));
    mx = fmaxf(mx, __shfl_xor(mx, 4));
    float e = expf(s - mx);
    float sum = e;
    sum += __shfl_xor(sum, 1); sum += __shfl_xor(sum, 2); sum += __shfl_xor(sum, 4);
    float a = e / sum;
    a += __shfl_xor(a, 8); a += __shfl_xor(a, 16); a += __shfl_xor(a, 32);
    if (lane < 8) wbar[0][w][lane] = a * 0.125f;
  }
  {
    float s = dot64(&tab[(2 * 8 + i) * AST + w * HD],
                    &tab[(3 * 8 + j) * AST + w * HD]);
    s = s * 0.125f + biasm[j][i];
    float mx = s;
    mx = fmaxf(mx, __shfl_xor(mx, 1));
    mx = fmaxf(mx, __shfl_xor(mx, 2));
    mx = fmaxf(mx, __shfl_xor(mx, 4));
    float e = expf(s - mx);
    float sum = e;
    sum += __shfl_xor(sum, 1); sum += __shfl_xor(sum, 2); sum += __shfl_xor(sum, 4);
    float a = e / sum;
    a += __shfl_xor(a, 8); a += __shfl_xor(a, 16); a += __shfl_xor(a, 32);
    if (lane < 8) wbar[1][w][lane] = a * 0.125f;
  }
  __syncthreads();

  // PV: side 0 -> mean_my (v from op cards, blk 2), side 1 -> mean_op
  // (v from my cards, blk 5). half2 loads, paired fp16 stores.
  {
    int p = tid & 127, side = tid >> 7;
    int h = p >> 5;   // head of elements 2p, 2p+1
    int tp = side ? 5 : 2;
    float s0 = 0.f, s1 = 0.f;
#pragma unroll
    for (int jj = 0; jj < 8; ++jj) {
      int card = cards[side ? jj : (8 + jj)];
      __half2 v2 = *(const __half2*)(proj + (size_t)card * 1536 + tp * 256 + p * 2);
      float2 vf = __half22float2(v2);
      float wv = wbar[side][h][jj];
      s0 += wv * vf.x;
      s1 += wv * vf.y;
    }
    __half2 o = __floats2half2_rn(s0, s1);
    *(__half2*)&meanf[(size_t)b * 512 + side * 256 + p * 2] = o;
  }
}

// ---------------------------------------------------------------------------
// K4: fused h1 GEMM (fp16 MFMA) + bias + LN + ReLU + head MLP + logit.
// M=16384,N=256,K=512. Block tile 32x256, BK=32. h1 never leaves LDS.
// ---------------------------------------------------------------------------
#define GSTR 40
__global__ __launch_bounds__(256) void gemm_ln_head(
    const __half* __restrict__ meanf, const __half* __restrict__ wcf,
    const float* __restrict__ bias_c,
    const float* __restrict__ ln_g, const float* __restrict__ ln_b,
    const float* __restrict__ w2T, const float* __restrict__ b2,
    const float* __restrict__ w3, const float* __restrict__ b3,
    float* __restrict__ out) {
  __shared__ __align__(16) char smem[33280];
  __half* sA = (__half*)smem;          // 32*40 halves
  __half* sB = sA + 32 * GSTR;         // 256*40 halves
  float* h1s = (float*)smem;           // reused post-GEMM: 32 x 260 f32

  int m0 = blockIdx.x * 32;
  int tid = threadIdx.x;
  int w = tid >> 6, lane = tid & 63;
  int lrow = lane & 15, lq = lane >> 4;
  int cb = w * 64;

  f32x4 acc[2][4] = {};
  int ar = tid >> 3;        // 0..31
  int ak = (tid & 7) * 4;   // 0..28

  for (int it = 0; it < 16; ++it) {
    int kb = it * 32;
    *(uint2*)&sA[ar * GSTR + ak] = *(const uint2*)&meanf[(size_t)(m0 + ar) * 512 + kb + ak];
#pragma unroll
    for (int s = 0; s < 8; ++s) {
      int n = s * 32 + ar;
      *(uint2*)&sB[n * GSTR + ak] = *(const uint2*)&wcf[(size_t)n * 512 + kb + ak];
    }
    __syncthreads();
    half8 a[2];
#pragma unroll
    for (int t = 0; t < 2; ++t)
      a[t] = *(const half8*)&sA[(t * 16 + lrow) * GSTR + lq * 8];
#pragma unroll
    for (int j = 0; j < 4; ++j) {
      half8 b = *(const half8*)&sB[(cb + j * 16 + lrow) * GSTR + lq * 8];
#pragma unroll
      for (int t = 0; t < 2; ++t)
        acc[t][j] = mfmaf16(a[t], b, acc[t][j]);
    }
    __syncthreads();
  }

  // h1 (+bias) into LDS
#pragma unroll
  for (int t = 0; t < 2; ++t)
#pragma unroll
    for (int j = 0; j < 4; ++j) {
      int col = cb + j * 16 + lrow;
      float bv = bias_c[col];
#pragma unroll
      for (int r = 0; r < 4; ++r) {
        int row = t * 16 + lq * 4 + r;
        h1s[row * 260 + col] = acc[t][j][r] + bv;
      }
    }
  __syncthreads();

  // LN + ReLU in place (wave w owns rows w*8..w*8+7)
  float g[4], bb[4];
#pragma unroll
  for (int s = 0; s < 4; ++s) {
    g[s]  = ln_g[lane + s * 64];
    bb[s] = ln_b[lane + s * 64];
  }
  for (int q = 0; q < 8; ++q) {
    int row = w * 8 + q;
    float v[4]; float sum = 0.f, ss = 0.f;
#pragma unroll
    for (int s = 0; s < 4; ++s) {
      v[s] = h1s[row * 260 + lane + s * 64];
      sum += v[s]; ss += v[s] * v[s];
    }
    for (int m = 1; m < 64; m <<= 1) {
      sum += __shfl_xor(sum, m);
      ss  += __shfl_xor(ss, m);
    }
    float mu = sum * (1.f / 256.f);
    float rs = rsqrtf(ss * (1.f / 256.f) - mu * mu + 1e-5f);
#pragma unroll
    for (int s = 0; s < 4; ++s) {
      float o = fmaxf((v[s] - mu) * rs * g[s] + bb[s], 0.f);
      h1s[row * 260 + lane + s * 64] = o;
    }
  }
  __syncthreads();

  // head: thread = (o = lane, row group qg = wave). h2 then logit reduce.
  {
    int o = lane, qg = w;
    float hacc[8] = {};
    for (int k = 0; k < 256; k += 4) {
      float wv0 = w2T[(k + 0) * 64 + o];
      float wv1 = w2T[(k + 1) * 64 + o];
      float wv2 = w2T[(k + 2) * 64 + o];
      float wv3 = w2T[(k + 3) * 64 + o];
#pragma unroll
      for (int jj = 0; jj < 8; ++jj) {
        float4 hv = *(const float4*)&h1s[(qg * 8 + jj) * 260 + k];
        hacc[jj] += hv.x * wv0 + hv.y * wv1 + hv.z * wv2 + hv.w * wv3;
      }
    }
    float b2v = b2[o], w3v = w3[o], b3v = b3[0];
#pragma unroll
    for (int jj = 0; jj < 8; ++jj) {
      float v = fmaxf(hacc[jj] + b2v, 0.f) * w3v;
      v += __shfl_xor(v, 1);  v += __shfl_xor(v, 2);
      v += __shfl_xor(v, 4);  v += __shfl_xor(v, 8);
      v += __shfl_xor(v, 16); v += __shfl_xor(v, 32);
      if (o == 0) out[m0 + qg * 8 + jj] = v + b3v;
    }
  }
}

// ---------------------------------------------------------------------------
extern "C" void kernel_launch(void* const* d_in, const int* in_sizes, int n_in,
                              void* d_out, int out_size, void* d_ws, size_t ws_size,
                              hipStream_t stream) {
  const float* x_real   = (const float*)d_in[0];
  const float* x_imag   = (const float*)d_in[1];
  const int*   my_decks = (const int*)d_in[2];
  const int*   op_decks = (const int*)d_in[3];
  const int*   adj      = (const int*)d_in[4];
  const float* in_w_my  = (const float*)d_in[5];
  const float* in_b_my  = (const float*)d_in[6];
  const float* out_w_my = (const float*)d_in[7];
  const float* out_b_my = (const float*)d_in[8];
  const float* in_w_op  = (const float*)d_in[9];
  const float* in_b_op  = (const float*)d_in[10];
  const float* out_w_op = (const float*)d_in[11];
  const float* out_b_op = (const float*)d_in[12];
  const float* w1       = (const float*)d_in[13];
  const float* b1       = (const float*)d_in[14];
  const float* ln_g     = (const float*)d_in[15];
  const float* ln_b     = (const float*)d_in[16];
  const float* w2       = (const float*)d_in[17];
  const float* b2       = (const float*)d_in[18];
  const float* w3       = (const float*)d_in[19];
  const float* b3       = (const float*)d_in[20];

  __half* projh  = (__half*)d_ws;            // 10000*1536 halves
  __half* meanf  = projh + 15360000;         // 16384*512
  __half* wcf    = meanf + 8388608;          // 256*512
  __half* embf   = wcf + 131072;             // 10000*256
  __half* wbf    = embf + 2560000;           // 1536*256
  float* bias_c  = (float*)(wbf + 393216);   // 256
  float* w2T     = bias_c + 256;             // 256*64
  float* out     = (float*)d_out;

  prep_all<<<5448, 256, 0, stream>>>(x_real, x_imag, in_w_my, in_w_op, w2,
                                     embf, wbf, w2T);

  dim3 g2((N_CARDS + 127) / 128, 1536 / 128);
  proj_mfma<<<g2, 256, 0, stream>>>(embf, wbf, in_b_my, in_b_op, projh);

  combine_w<<<dim3(257, 2), 256, 0, stream>>>(w1, b1, out_w_my, out_w_op,
                                              out_b_my, out_b_op, wcf, bias_c);

  attn_kernel<<<BATCH, 256, 0, stream>>>(projh, my_decks, op_decks, adj, meanf);

  gemm_ln_head<<<BATCH / 32, 256, 0, stream>>>(meanf, wcf, bias_c,
                                               ln_g, ln_b, w2T, b2, w3, b3, out);
}